// Round 1
// baseline (3929.784 us; speedup 1.0000x reference)
//
#include <hip/hip_runtime.h>

#define RELS 3
#define IN1  3
#define HID  16
#define OUT2 8

// ---------------- W = comp @ basis (tiny) ----------------
__global__ void k_compute_W(const float* __restrict__ basis1, const float* __restrict__ comp1,
                            const float* __restrict__ basis2, const float* __restrict__ comp2,
                            int B, float* __restrict__ W1, float* __restrict__ W2) {
    int tid = threadIdx.x;
    if (tid < RELS * IN1 * HID) {
        int r = tid / (IN1 * HID), io = tid % (IN1 * HID);
        float acc = 0.f;
        for (int b = 0; b < B; ++b) acc += comp1[r * B + b] * basis1[b * IN1 * HID + io];
        W1[tid] = acc;
    }
    if (tid < RELS * HID * OUT2) {
        int r = tid / (HID * OUT2), io = tid % (HID * OUT2);
        float acc = 0.f;
        for (int b = 0; b < B; ++b) acc += comp2[r * B + b] * basis2[b * HID * OUT2 + io];
        W2[tid] = acc;
    }
}

// ---------------- layer1 scatter: raw x (3 floats) + count ----------------
__global__ void k_scatter1(const int* __restrict__ src, const int* __restrict__ dst,
                           const int* __restrict__ et, const float* __restrict__ x,
                           float* __restrict__ sums_x, float* __restrict__ cnt,
                           int N, int E) {
    int e = blockIdx.x * blockDim.x + threadIdx.x;
    if (e >= E) return;
    int s = src[e], d = dst[e], t = et[e];
    int seg = t * N + d;
    float x0 = x[3 * s + 0], x1 = x[3 * s + 1], x2 = x[3 * s + 2];
    float* b = sums_x + (size_t)seg * 3;
    unsafeAtomicAdd(b + 0, x0);
    unsafeAtomicAdd(b + 1, x1);
    unsafeAtomicAdd(b + 2, x2);
    unsafeAtomicAdd(cnt + seg, 1.0f);
}

// ---------------- layer1 finalize: mean -> @W1 -> +x@root1+bias -> relu -> h, and xw2 = h@W2[r] ----------------
__global__ void k_finalize1(const float* __restrict__ x, const float* __restrict__ sums_x,
                            const float* __restrict__ cnt,
                            const float* __restrict__ W1, const float* __restrict__ root1,
                            const float* __restrict__ bias1, const float* __restrict__ W2,
                            float* __restrict__ h, float* __restrict__ xw2, int N) {
    __shared__ float sW1[RELS * IN1 * HID];
    __shared__ float sR1[IN1 * HID];
    __shared__ float sB1[HID];
    __shared__ float sW2[RELS * HID * OUT2];
    for (int i = threadIdx.x; i < RELS * IN1 * HID; i += blockDim.x) sW1[i] = W1[i];
    for (int i = threadIdx.x; i < IN1 * HID; i += blockDim.x) sR1[i] = root1[i];
    for (int i = threadIdx.x; i < HID; i += blockDim.x) sB1[i] = bias1[i];
    for (int i = threadIdx.x; i < RELS * HID * OUT2; i += blockDim.x) sW2[i] = W2[i];
    __syncthreads();
    int n = blockIdx.x * blockDim.x + threadIdx.x;
    if (n >= N) return;

    float acc[HID];
#pragma unroll
    for (int o = 0; o < HID; ++o) acc[o] = sB1[o];
    float xv0 = x[3 * n + 0], xv1 = x[3 * n + 1], xv2 = x[3 * n + 2];
#pragma unroll
    for (int o = 0; o < HID; ++o)
        acc[o] += xv0 * sR1[0 * HID + o] + xv1 * sR1[1 * HID + o] + xv2 * sR1[2 * HID + o];

    for (int r = 0; r < RELS; ++r) {
        int seg = r * N + n;
        float inv = 1.0f / fmaxf(cnt[seg], 1.0f);
        float m0 = sums_x[(size_t)seg * 3 + 0] * inv;
        float m1 = sums_x[(size_t)seg * 3 + 1] * inv;
        float m2 = sums_x[(size_t)seg * 3 + 2] * inv;
        const float* w = sW1 + r * IN1 * HID;
#pragma unroll
        for (int o = 0; o < HID; ++o)
            acc[o] += m0 * w[0 * HID + o] + m1 * w[1 * HID + o] + m2 * w[2 * HID + o];
    }

    float hv[HID];
#pragma unroll
    for (int o = 0; o < HID; ++o) {
        hv[o] = fmaxf(acc[o], 0.0f);
    }
#pragma unroll
    for (int o = 0; o < HID; ++o) h[(size_t)n * HID + o] = hv[o];

    for (int r = 0; r < RELS; ++r) {
        float o8[OUT2];
#pragma unroll
        for (int o = 0; o < OUT2; ++o) o8[o] = 0.f;
        const float* w = sW2 + r * HID * OUT2;
#pragma unroll
        for (int i = 0; i < HID; ++i)
#pragma unroll
            for (int o = 0; o < OUT2; ++o) o8[o] += hv[i] * w[i * OUT2 + o];
        float* dstp = xw2 + ((size_t)r * N + n) * OUT2;
#pragma unroll
        for (int o = 0; o < OUT2; ++o) dstp[o] = o8[o];
    }
}

// ---------------- layer2 scatter: xw2[t, src] (8 floats) ----------------
__global__ void k_scatter2(const int* __restrict__ src, const int* __restrict__ dst,
                           const int* __restrict__ et, const float* __restrict__ xw2,
                           float* __restrict__ sums2, int N, int E) {
    int e = blockIdx.x * blockDim.x + threadIdx.x;
    if (e >= E) return;
    int s = src[e], d = dst[e], t = et[e];
    const float* g = xw2 + ((size_t)t * N + s) * OUT2;
    float4 a = *reinterpret_cast<const float4*>(g);
    float4 b = *reinterpret_cast<const float4*>(g + 4);
    float* o = sums2 + ((size_t)t * N + d) * OUT2;
    unsafeAtomicAdd(o + 0, a.x);
    unsafeAtomicAdd(o + 1, a.y);
    unsafeAtomicAdd(o + 2, a.z);
    unsafeAtomicAdd(o + 3, a.w);
    unsafeAtomicAdd(o + 4, b.x);
    unsafeAtomicAdd(o + 5, b.y);
    unsafeAtomicAdd(o + 6, b.z);
    unsafeAtomicAdd(o + 7, b.w);
}

// ---------------- layer2 finalize: mean-sum + h@root2 + bias2 -> log_softmax ----------------
__global__ void k_finalize2(const float* __restrict__ h, const float* __restrict__ sums2,
                            const float* __restrict__ cnt, const float* __restrict__ root2,
                            const float* __restrict__ bias2, float* __restrict__ out, int N) {
    __shared__ float sR2[HID * OUT2];
    __shared__ float sB2[OUT2];
    for (int i = threadIdx.x; i < HID * OUT2; i += blockDim.x) sR2[i] = root2[i];
    for (int i = threadIdx.x; i < OUT2; i += blockDim.x) sB2[i] = bias2[i];
    __syncthreads();
    int n = blockIdx.x * blockDim.x + threadIdx.x;
    if (n >= N) return;

    float acc[OUT2];
#pragma unroll
    for (int o = 0; o < OUT2; ++o) acc[o] = sB2[o];

    const float4* hp = reinterpret_cast<const float4*>(h + (size_t)n * HID);
    float hv[HID];
#pragma unroll
    for (int q = 0; q < 4; ++q) {
        float4 v = hp[q];
        hv[4 * q + 0] = v.x; hv[4 * q + 1] = v.y; hv[4 * q + 2] = v.z; hv[4 * q + 3] = v.w;
    }
#pragma unroll
    for (int i = 0; i < HID; ++i)
#pragma unroll
        for (int o = 0; o < OUT2; ++o) acc[o] += hv[i] * sR2[i * OUT2 + o];

    for (int r = 0; r < RELS; ++r) {
        int seg = r * N + n;
        float inv = 1.0f / fmaxf(cnt[seg], 1.0f);
        const float* sp = sums2 + (size_t)seg * OUT2;
#pragma unroll
        for (int o = 0; o < OUT2; ++o) acc[o] += sp[o] * inv;
    }

    float mx = acc[0];
#pragma unroll
    for (int o = 1; o < OUT2; ++o) mx = fmaxf(mx, acc[o]);
    float s = 0.f;
#pragma unroll
    for (int o = 0; o < OUT2; ++o) s += expf(acc[o] - mx);
    float lse = logf(s) + mx;
    float* op = out + (size_t)n * OUT2;
#pragma unroll
    for (int o = 0; o < OUT2; ++o) op[o] = acc[o] - lse;
}

extern "C" void kernel_launch(void* const* d_in, const int* in_sizes, int n_in,
                              void* d_out, int out_size, void* d_ws, size_t ws_size,
                              hipStream_t stream) {
    const float* x      = (const float*)d_in[0];
    const int*   eidx   = (const int*)d_in[1];
    const int*   etype  = (const int*)d_in[2];
    const float* basis1 = (const float*)d_in[3];
    const float* comp1  = (const float*)d_in[4];
    const float* root1  = (const float*)d_in[5];
    const float* bias1  = (const float*)d_in[6];
    const float* basis2 = (const float*)d_in[7];
    const float* comp2  = (const float*)d_in[8];
    const float* root2  = (const float*)d_in[9];
    const float* bias2  = (const float*)d_in[10];
    float* out = (float*)d_out;

    const int N = in_sizes[0] / IN1;
    const int E = in_sizes[2];
    const int B = in_sizes[3] / (IN1 * HID);

    const int* src = eidx;
    const int* dst = eidx + E;

    // workspace layout (floats), 16-float (64B) aligned chunks
    float* ws = (float*)d_ws;
    size_t off = 0;
    float* W1 = ws + off;      off += 160;                       // 144 used
    float* W2 = ws + off;      off += 384;
    size_t zero_start = off;
    float* cnt = ws + off;     off += ((size_t)RELS * N + 15) & ~(size_t)15;
    float* sums_x = ws + off;  off += ((size_t)RELS * N * 3 + 15) & ~(size_t)15;
    float* sums2 = ws + off;   off += (size_t)RELS * N * OUT2;
    size_t zero_end = off;
    float* h = ws + off;       off += (size_t)N * HID;
    float* xw2 = ws + off;     off += (size_t)RELS * N * OUT2;

    hipMemsetAsync(ws + zero_start, 0, (zero_end - zero_start) * sizeof(float), stream);

    k_compute_W<<<1, 384, 0, stream>>>(basis1, comp1, basis2, comp2, B, W1, W2);

    int blkE = 256, grdE = (E + blkE - 1) / blkE;
    k_scatter1<<<grdE, blkE, 0, stream>>>(src, dst, etype, x, sums_x, cnt, N, E);

    int blkN = 256, grdN = (N + blkN - 1) / blkN;
    k_finalize1<<<grdN, blkN, 0, stream>>>(x, sums_x, cnt, W1, root1, bias1, W2, h, xw2, N);

    k_scatter2<<<grdE, blkE, 0, stream>>>(src, dst, etype, xw2, sums2, N, E);

    k_finalize2<<<grdN, blkN, 0, stream>>>(h, sums2, cnt, root2, bias2, out, N);
}

// Round 2
// 961.247 us; speedup vs baseline: 4.0882x; 4.0882x over previous
//
#include <hip/hip_runtime.h>

#define RELS 3
#define IN1  3
#define HID  16
#define OUT2 8

#define SCAN_BLOCK 256
#define SCAN_ITEMS 4          // 1024 elements per block
#define SCAN_TILE  (SCAN_BLOCK * SCAN_ITEMS)

// ---------------- W = comp @ basis (tiny) ----------------
__global__ void k_compute_W(const float* __restrict__ basis1, const float* __restrict__ comp1,
                            const float* __restrict__ basis2, const float* __restrict__ comp2,
                            int B, float* __restrict__ W1, float* __restrict__ W2) {
    int tid = threadIdx.x;
    if (tid < RELS * IN1 * HID) {
        int r = tid / (IN1 * HID), io = tid % (IN1 * HID);
        float acc = 0.f;
        for (int b = 0; b < B; ++b) acc += comp1[r * B + b] * basis1[b * IN1 * HID + io];
        W1[tid] = acc;
    }
    if (tid < RELS * HID * OUT2) {
        int r = tid / (HID * OUT2), io = tid % (HID * OUT2);
        float acc = 0.f;
        for (int b = 0; b < B; ++b) acc += comp2[r * B + b] * basis2[b * HID * OUT2 + io];
        W2[tid] = acc;
    }
}

// ---------------- CSR build: histogram ----------------
__global__ void k_hist(const int* __restrict__ dst, const int* __restrict__ et,
                       int* __restrict__ deg, int N, int E) {
    int e = blockIdx.x * blockDim.x + threadIdx.x;
    if (e >= E) return;
    atomicAdd(&deg[et[e] * N + dst[e]], 1);
}

// ---------------- CSR build: block-level exclusive scan ----------------
__global__ void k_scan_block(const int* __restrict__ deg, int* __restrict__ off,
                             int* __restrict__ bsums, int S) {
    __shared__ int lds[SCAN_BLOCK];
    int base = blockIdx.x * SCAN_TILE + threadIdx.x * SCAN_ITEMS;
    int v[SCAN_ITEMS];
    int tot = 0;
#pragma unroll
    for (int k = 0; k < SCAN_ITEMS; ++k) {
        int i = base + k;
        v[k] = (i < S) ? deg[i] : 0;
        tot += v[k];
    }
    lds[threadIdx.x] = tot;
    __syncthreads();
    for (int d = 1; d < SCAN_BLOCK; d <<= 1) {
        int val = lds[threadIdx.x];
        int add = (threadIdx.x >= d) ? lds[threadIdx.x - d] : 0;
        __syncthreads();
        lds[threadIdx.x] = val + add;
        __syncthreads();
    }
    int excl = (threadIdx.x == 0) ? 0 : lds[threadIdx.x - 1];
    if (threadIdx.x == SCAN_BLOCK - 1) bsums[blockIdx.x] = lds[SCAN_BLOCK - 1];
    int run = excl;
#pragma unroll
    for (int k = 0; k < SCAN_ITEMS; ++k) {
        int i = base + k;
        if (i < S) off[i] = run;
        run += v[k];
    }
}

// single-block exclusive scan of block sums (NB <= 1024)
__global__ void k_scan_top(int* __restrict__ bsums, int NB) {
    __shared__ int lds[1024];
    int t = threadIdx.x;
    lds[t] = (t < NB) ? bsums[t] : 0;
    __syncthreads();
    for (int d = 1; d < 1024; d <<= 1) {
        int val = lds[t];
        int add = (t >= d) ? lds[t - d] : 0;
        __syncthreads();
        lds[t] = val + add;
        __syncthreads();
    }
    int excl = (t == 0) ? 0 : lds[t - 1];
    if (t < NB) bsums[t] = excl;
}

__global__ void k_scan_add(int* __restrict__ off, int* __restrict__ cursor,
                           const int* __restrict__ bsums, int S, int E) {
    int i = blockIdx.x * blockDim.x + threadIdx.x;
    if (i < S) {
        int o = off[i] + bsums[i / SCAN_TILE];
        off[i] = o;
        cursor[i] = o;
    }
    if (i == 0) off[S] = E;
}

// ---------------- CSR build: placement ----------------
__global__ void k_place(const int* __restrict__ src, const int* __restrict__ dst,
                        const int* __restrict__ et, int* __restrict__ cursor,
                        int* __restrict__ csr, int N, int E) {
    int e = blockIdx.x * blockDim.x + threadIdx.x;
    if (e >= E) return;
    int seg = et[e] * N + dst[e];
    int slot = atomicAdd(&cursor[seg], 1);
    csr[slot] = src[e];
}

// ---------------- layer1 fused: gather mean(x) -> @W1 + x@root1 + bias -> relu
//                  -> emit xw2 = h@W2[r] and hroot = h@root2 ----------------
__global__ void k_layer1(const float* __restrict__ x, const int* __restrict__ off,
                         const int* __restrict__ csr,
                         const float* __restrict__ W1, const float* __restrict__ root1,
                         const float* __restrict__ bias1, const float* __restrict__ W2,
                         const float* __restrict__ root2,
                         float* __restrict__ xw2, float* __restrict__ hroot, int N) {
    __shared__ float sW1[RELS * IN1 * HID];
    __shared__ float sR1[IN1 * HID];
    __shared__ float sB1[HID];
    __shared__ float sW2[RELS * HID * OUT2];
    __shared__ float sR2[HID * OUT2];
    for (int i = threadIdx.x; i < RELS * IN1 * HID; i += blockDim.x) sW1[i] = W1[i];
    for (int i = threadIdx.x; i < IN1 * HID; i += blockDim.x) sR1[i] = root1[i];
    for (int i = threadIdx.x; i < HID; i += blockDim.x) sB1[i] = bias1[i];
    for (int i = threadIdx.x; i < RELS * HID * OUT2; i += blockDim.x) sW2[i] = W2[i];
    for (int i = threadIdx.x; i < HID * OUT2; i += blockDim.x) sR2[i] = root2[i];
    __syncthreads();
    int n = blockIdx.x * blockDim.x + threadIdx.x;
    if (n >= N) return;

    float acc[HID];
    float xv0 = x[3 * n + 0], xv1 = x[3 * n + 1], xv2 = x[3 * n + 2];
#pragma unroll
    for (int o = 0; o < HID; ++o)
        acc[o] = sB1[o] + xv0 * sR1[0 * HID + o] + xv1 * sR1[1 * HID + o] + xv2 * sR1[2 * HID + o];

    for (int r = 0; r < RELS; ++r) {
        int a = off[r * N + n], b = off[r * N + n + 1];
        float s0 = 0.f, s1 = 0.f, s2 = 0.f;
        for (int e = a; e < b; ++e) {
            int s = csr[e];
            s0 += x[3 * s + 0];
            s1 += x[3 * s + 1];
            s2 += x[3 * s + 2];
        }
        float inv = 1.0f / fmaxf((float)(b - a), 1.0f);
        s0 *= inv; s1 *= inv; s2 *= inv;
        const float* w = sW1 + r * IN1 * HID;
#pragma unroll
        for (int o = 0; o < HID; ++o)
            acc[o] += s0 * w[0 * HID + o] + s1 * w[1 * HID + o] + s2 * w[2 * HID + o];
    }

    float hv[HID];
#pragma unroll
    for (int o = 0; o < HID; ++o) hv[o] = fmaxf(acc[o], 0.0f);

    // xw2[r][n][:] = hv @ W2[r]
    for (int r = 0; r < RELS; ++r) {
        float o8[OUT2];
#pragma unroll
        for (int o = 0; o < OUT2; ++o) o8[o] = 0.f;
        const float* w = sW2 + r * HID * OUT2;
#pragma unroll
        for (int i = 0; i < HID; ++i)
#pragma unroll
            for (int o = 0; o < OUT2; ++o) o8[o] += hv[i] * w[i * OUT2 + o];
        float* dp = xw2 + ((size_t)r * N + n) * OUT2;
        float4 lo = {o8[0], o8[1], o8[2], o8[3]};
        float4 hi = {o8[4], o8[5], o8[6], o8[7]};
        *reinterpret_cast<float4*>(dp) = lo;
        *reinterpret_cast<float4*>(dp + 4) = hi;
    }
    // hroot[n][:] = hv @ root2
    {
        float o8[OUT2];
#pragma unroll
        for (int o = 0; o < OUT2; ++o) o8[o] = 0.f;
#pragma unroll
        for (int i = 0; i < HID; ++i)
#pragma unroll
            for (int o = 0; o < OUT2; ++o) o8[o] += hv[i] * sR2[i * OUT2 + o];
        float* dp = hroot + (size_t)n * OUT2;
        float4 lo = {o8[0], o8[1], o8[2], o8[3]};
        float4 hi = {o8[4], o8[5], o8[6], o8[7]};
        *reinterpret_cast<float4*>(dp) = lo;
        *reinterpret_cast<float4*>(dp + 4) = hi;
    }
}

// ---------------- layer2 fused: gather mean(xw2) + hroot + bias2 -> log_softmax ----------------
__global__ void k_layer2(const int* __restrict__ off, const int* __restrict__ csr,
                         const float* __restrict__ xw2, const float* __restrict__ hroot,
                         const float* __restrict__ bias2, float* __restrict__ out, int N) {
    __shared__ float sB2[OUT2];
    for (int i = threadIdx.x; i < OUT2; i += blockDim.x) sB2[i] = bias2[i];
    __syncthreads();
    int n = blockIdx.x * blockDim.x + threadIdx.x;
    if (n >= N) return;

    float acc[OUT2];
    const float4* hp = reinterpret_cast<const float4*>(hroot + (size_t)n * OUT2);
    float4 h0 = hp[0], h1 = hp[1];
    acc[0] = sB2[0] + h0.x; acc[1] = sB2[1] + h0.y;
    acc[2] = sB2[2] + h0.z; acc[3] = sB2[3] + h0.w;
    acc[4] = sB2[4] + h1.x; acc[5] = sB2[5] + h1.y;
    acc[6] = sB2[6] + h1.z; acc[7] = sB2[7] + h1.w;

    for (int r = 0; r < RELS; ++r) {
        int a = off[r * N + n], b = off[r * N + n + 1];
        float s8[OUT2];
#pragma unroll
        for (int o = 0; o < OUT2; ++o) s8[o] = 0.f;
        const float* basep = xw2 + (size_t)r * N * OUT2;
        for (int e = a; e < b; ++e) {
            int s = csr[e];
            const float4* p = reinterpret_cast<const float4*>(basep + (size_t)s * OUT2);
            float4 v0 = p[0], v1 = p[1];
            s8[0] += v0.x; s8[1] += v0.y; s8[2] += v0.z; s8[3] += v0.w;
            s8[4] += v1.x; s8[5] += v1.y; s8[6] += v1.z; s8[7] += v1.w;
        }
        float inv = 1.0f / fmaxf((float)(b - a), 1.0f);
#pragma unroll
        for (int o = 0; o < OUT2; ++o) acc[o] += s8[o] * inv;
    }

    float mx = acc[0];
#pragma unroll
    for (int o = 1; o < OUT2; ++o) mx = fmaxf(mx, acc[o]);
    float s = 0.f;
#pragma unroll
    for (int o = 0; o < OUT2; ++o) s += expf(acc[o] - mx);
    float lse = logf(s) + mx;
    float* op = out + (size_t)n * OUT2;
#pragma unroll
    for (int o = 0; o < OUT2; ++o) op[o] = acc[o] - lse;
}

extern "C" void kernel_launch(void* const* d_in, const int* in_sizes, int n_in,
                              void* d_out, int out_size, void* d_ws, size_t ws_size,
                              hipStream_t stream) {
    const float* x      = (const float*)d_in[0];
    const int*   eidx   = (const int*)d_in[1];
    const int*   etype  = (const int*)d_in[2];
    const float* basis1 = (const float*)d_in[3];
    const float* comp1  = (const float*)d_in[4];
    const float* root1  = (const float*)d_in[5];
    const float* bias1  = (const float*)d_in[6];
    const float* basis2 = (const float*)d_in[7];
    const float* comp2  = (const float*)d_in[8];
    const float* root2  = (const float*)d_in[9];
    const float* bias2  = (const float*)d_in[10];
    float* out = (float*)d_out;

    const int N = in_sizes[0] / IN1;
    const int E = in_sizes[2];
    const int B = in_sizes[3] / (IN1 * HID);
    const int S = RELS * N;

    const int* src = eidx;
    const int* dst = eidx + E;

    // workspace layout (4-byte words), 16-word aligned chunks
    char* wsb = (char*)d_ws;
    size_t off_w = 0;
    auto alloc_w = [&](size_t words) {
        void* p = wsb + off_w * 4;
        off_w += (words + 15) & ~(size_t)15;
        return p;
    };
    int*   deg    = (int*)alloc_w(S);
    int*   offp   = (int*)alloc_w(S + 1);
    int*   cursor = (int*)alloc_w(S);
    int*   bsums  = (int*)alloc_w(1024);
    int*   csr    = (int*)alloc_w(E);
    float* W1     = (float*)alloc_w(RELS * IN1 * HID);
    float* W2     = (float*)alloc_w(RELS * HID * OUT2);
    float* xw2    = (float*)alloc_w((size_t)S * OUT2);
    float* hroot  = (float*)alloc_w((size_t)N * OUT2);

    hipMemsetAsync(deg, 0, (size_t)S * sizeof(int), stream);

    k_compute_W<<<1, 384, 0, stream>>>(basis1, comp1, basis2, comp2, B, W1, W2);

    int blkE = 256, grdE = (E + blkE - 1) / blkE;
    k_hist<<<grdE, blkE, 0, stream>>>(dst, etype, deg, N, E);

    int NB = (S + SCAN_TILE - 1) / SCAN_TILE;   // 586 for N=200k
    k_scan_block<<<NB, SCAN_BLOCK, 0, stream>>>(deg, offp, bsums, S);
    k_scan_top<<<1, 1024, 0, stream>>>(bsums, NB);
    int grdS = (S + 255) / 256;
    k_scan_add<<<grdS, 256, 0, stream>>>(offp, cursor, bsums, S, E);

    k_place<<<grdE, blkE, 0, stream>>>(src, dst, etype, cursor, csr, N, E);

    int blkN = 256, grdN = (N + blkN - 1) / blkN;
    k_layer1<<<grdN, blkN, 0, stream>>>(x, offp, csr, W1, root1, bias1, W2, root2,
                                        xw2, hroot, N);
    k_layer2<<<grdN, blkN, 0, stream>>>(offp, csr, xw2, hroot, bias2, out, N);
}

// Round 3
// 703.215 us; speedup vs baseline: 5.5883x; 1.3669x over previous
//
#include <hip/hip_runtime.h>

#define RELS 3
#define IN1  3
#define HID  16
#define OUT2 8

#define BW     256                 // dsts per bucket (== 1<<8, shift below)
#define MAXB   1024                // max buckets supported by LDS arrays
#define TILE_T 256
#define TILE_I 32
#define TILE   (TILE_T * TILE_I)   // 8192 edges per partition block

#define SCAN_BLOCK 256
#define SCAN_ITEMS 8
#define SCAN_TILE  (SCAN_BLOCK * SCAN_ITEMS)   // 2048

#define CMAX 10240                 // LDS staging capacity in pass C (edges)

// ---------------- W = comp @ basis (tiny) ----------------
__global__ void k_compute_W(const float* __restrict__ basis1, const float* __restrict__ comp1,
                            const float* __restrict__ basis2, const float* __restrict__ comp2,
                            int B, float* __restrict__ W1, float* __restrict__ W2) {
    int tid = threadIdx.x;
    if (tid < RELS * IN1 * HID) {
        int r = tid / (IN1 * HID), io = tid % (IN1 * HID);
        float acc = 0.f;
        for (int b = 0; b < B; ++b) acc += comp1[r * B + b] * basis1[b * IN1 * HID + io];
        W1[tid] = acc;
    }
    if (tid < RELS * HID * OUT2) {
        int r = tid / (HID * OUT2), io = tid % (HID * OUT2);
        float acc = 0.f;
        for (int b = 0; b < B; ++b) acc += comp2[r * B + b] * basis2[b * HID * OUT2 + io];
        W2[tid] = acc;
    }
}

// ---------------- pass A: per-block bucket histogram (LDS atomics only) ----------------
__global__ void k_part_count(const int* __restrict__ dst, int* __restrict__ cnt,
                             int E, int NBUCK, int NT) {
    __shared__ int hist[MAXB];
    for (int i = threadIdx.x; i < NBUCK; i += TILE_T) hist[i] = 0;
    __syncthreads();
    int base = blockIdx.x * TILE;
#pragma unroll 4
    for (int k = 0; k < TILE_I; ++k) {
        int e = base + k * TILE_T + threadIdx.x;
        if (e < E) atomicAdd(&hist[dst[e] >> 8], 1);
    }
    __syncthreads();
    for (int b = threadIdx.x; b < NBUCK; b += TILE_T)
        cnt[(size_t)b * NT + blockIdx.x] = hist[b];
}

// ---------------- scan (in-place capable) ----------------
__global__ void k_scan_block(int* __restrict__ data, int* __restrict__ bsums, int S) {
    __shared__ int lds[SCAN_BLOCK];
    int base = blockIdx.x * SCAN_TILE + threadIdx.x * SCAN_ITEMS;
    int v[SCAN_ITEMS];
    int tot = 0;
#pragma unroll
    for (int k = 0; k < SCAN_ITEMS; ++k) {
        int i = base + k;
        v[k] = (i < S) ? data[i] : 0;
        tot += v[k];
    }
    lds[threadIdx.x] = tot;
    __syncthreads();
    for (int d = 1; d < SCAN_BLOCK; d <<= 1) {
        int val = lds[threadIdx.x];
        int add = (threadIdx.x >= d) ? lds[threadIdx.x - d] : 0;
        __syncthreads();
        lds[threadIdx.x] = val + add;
        __syncthreads();
    }
    int excl = (threadIdx.x == 0) ? 0 : lds[threadIdx.x - 1];
    if (threadIdx.x == SCAN_BLOCK - 1) bsums[blockIdx.x] = lds[SCAN_BLOCK - 1];
    int run = excl;
#pragma unroll
    for (int k = 0; k < SCAN_ITEMS; ++k) {
        int i = base + k;
        if (i < S) data[i] = run;
        run += v[k];
    }
}

__global__ void k_scan_top(int* __restrict__ bsums, int NB) {
    __shared__ int lds[1024];
    int t = threadIdx.x;
    lds[t] = (t < NB) ? bsums[t] : 0;
    __syncthreads();
    for (int d = 1; d < 1024; d <<= 1) {
        int val = lds[t];
        int add = (t >= d) ? lds[t - d] : 0;
        __syncthreads();
        lds[t] = val + add;
        __syncthreads();
    }
    int excl = (t == 0) ? 0 : lds[t - 1];
    if (t < NB) bsums[t] = excl;
}

__global__ void k_scan_add(int* __restrict__ data, const int* __restrict__ bsums, int S) {
    int i = blockIdx.x * blockDim.x + threadIdx.x;
    if (i < S) data[i] += bsums[i / SCAN_TILE];
}

// ---------------- pass B: scatter packed edges into bucket order (LDS atomics only) -----
__global__ void k_part_scatter(const int* __restrict__ src, const int* __restrict__ dst,
                               const int* __restrict__ et, const int* __restrict__ off_e,
                               unsigned* __restrict__ part, int E, int NBUCK, int NT) {
    __shared__ int cursor[MAXB];
    for (int i = threadIdx.x; i < NBUCK; i += TILE_T)
        cursor[i] = off_e[(size_t)i * NT + blockIdx.x];
    __syncthreads();
    int base = blockIdx.x * TILE;
#pragma unroll 4
    for (int k = 0; k < TILE_I; ++k) {
        int e = base + k * TILE_T + threadIdx.x;
        if (e < E) {
            int d = dst[e];
            int b = d >> 8;
            int pos = atomicAdd(&cursor[b], 1);
            unsigned pk = ((unsigned)(d & 255) << 20) | ((unsigned)et[e] << 18) | (unsigned)src[e];
            part[pos] = pk;
        }
    }
}

// ---------------- pass C: per-bucket counting sort -> dst-grouped CSR + offsets ---------
__global__ void k_bucket_sort(const int* __restrict__ off_e, const unsigned* __restrict__ part,
                              unsigned* __restrict__ csr, int* __restrict__ off_g,
                              int E, int NBUCK, int NT) {
    __shared__ int cnt[BW];
    __shared__ int inc[BW];
    __shared__ int cur[BW];
    __shared__ unsigned loc[CMAX];
    int b = blockIdx.x;
    int bs = off_e[(size_t)b * NT];
    int be = (b + 1 < NBUCK) ? off_e[(size_t)(b + 1) * NT] : E;
    int sz = be - bs;
    int t = threadIdx.x;
    cnt[t] = 0;
    __syncthreads();
    for (int i = t; i < sz; i += BW)
        atomicAdd(&cnt[part[bs + i] >> 20], 1);
    __syncthreads();
    inc[t] = cnt[t];
    __syncthreads();
    for (int d = 1; d < BW; d <<= 1) {
        int val = inc[t];
        int add = (t >= d) ? inc[t - d] : 0;
        __syncthreads();
        inc[t] = val + add;
        __syncthreads();
    }
    int excl = (t == 0) ? 0 : inc[t - 1];
    cur[t] = excl;
    off_g[b * BW + t] = bs + excl;
    if (b == NBUCK - 1 && t == 0) off_g[NBUCK * BW] = E;
    __syncthreads();
    if (sz <= CMAX) {
        for (int i = t; i < sz; i += BW) {
            unsigned v = part[bs + i];
            int p = atomicAdd(&cur[v >> 20], 1);
            loc[p] = v & 0xFFFFF;
        }
        __syncthreads();
        for (int i = t; i < sz; i += BW) csr[bs + i] = loc[i];
    } else {
        for (int i = t; i < sz; i += BW) {
            unsigned v = part[bs + i];
            int p = atomicAdd(&cur[v >> 20], 1);
            csr[bs + p] = v & 0xFFFFF;
        }
    }
}

// ---------------- layer1 fused ----------------
__global__ void k_layer1(const float* __restrict__ x, const int* __restrict__ off_g,
                         const unsigned* __restrict__ csr,
                         const float* __restrict__ W1, const float* __restrict__ root1,
                         const float* __restrict__ bias1, const float* __restrict__ W2,
                         const float* __restrict__ root2,
                         float* __restrict__ xw2, float* __restrict__ hroot, int N) {
    __shared__ float sW1[RELS * IN1 * HID];
    __shared__ float sR1[IN1 * HID];
    __shared__ float sB1[HID];
    __shared__ float sW2[RELS * HID * OUT2];
    __shared__ float sR2[HID * OUT2];
    for (int i = threadIdx.x; i < RELS * IN1 * HID; i += blockDim.x) sW1[i] = W1[i];
    for (int i = threadIdx.x; i < IN1 * HID; i += blockDim.x) sR1[i] = root1[i];
    for (int i = threadIdx.x; i < HID; i += blockDim.x) sB1[i] = bias1[i];
    for (int i = threadIdx.x; i < RELS * HID * OUT2; i += blockDim.x) sW2[i] = W2[i];
    for (int i = threadIdx.x; i < HID * OUT2; i += blockDim.x) sR2[i] = root2[i];
    __syncthreads();
    int n = blockIdx.x * blockDim.x + threadIdx.x;
    if (n >= N) return;

    int a = off_g[n], bnd = off_g[n + 1];
    float s00 = 0.f, s01 = 0.f, s02 = 0.f;
    float s10 = 0.f, s11 = 0.f, s12 = 0.f;
    float s20 = 0.f, s21 = 0.f, s22 = 0.f;
    float c0 = 0.f, c1 = 0.f, c2 = 0.f;
    for (int e = a; e < bnd; ++e) {
        unsigned v = csr[e];
        int ty = (v >> 18) & 3;
        int s = v & 0x3FFFF;
        float x0 = x[3 * s + 0], x1 = x[3 * s + 1], x2 = x[3 * s + 2];
        float m0 = (ty == 0) ? 1.f : 0.f;
        float m1 = (ty == 1) ? 1.f : 0.f;
        float m2 = (ty == 2) ? 1.f : 0.f;
        s00 += m0 * x0; s01 += m0 * x1; s02 += m0 * x2; c0 += m0;
        s10 += m1 * x0; s11 += m1 * x1; s12 += m1 * x2; c1 += m1;
        s20 += m2 * x0; s21 += m2 * x1; s22 += m2 * x2; c2 += m2;
    }
    float i0 = 1.0f / fmaxf(c0, 1.0f);
    float i1 = 1.0f / fmaxf(c1, 1.0f);
    float i2 = 1.0f / fmaxf(c2, 1.0f);
    s00 *= i0; s01 *= i0; s02 *= i0;
    s10 *= i1; s11 *= i1; s12 *= i1;
    s20 *= i2; s21 *= i2; s22 *= i2;

    float acc[HID];
    float xv0 = x[3 * n + 0], xv1 = x[3 * n + 1], xv2 = x[3 * n + 2];
#pragma unroll
    for (int o = 0; o < HID; ++o)
        acc[o] = sB1[o] + xv0 * sR1[0 * HID + o] + xv1 * sR1[1 * HID + o] + xv2 * sR1[2 * HID + o];
#pragma unroll
    for (int o = 0; o < HID; ++o) {
        acc[o] += s00 * sW1[0 * IN1 * HID + 0 * HID + o] + s01 * sW1[0 * IN1 * HID + 1 * HID + o] + s02 * sW1[0 * IN1 * HID + 2 * HID + o];
        acc[o] += s10 * sW1[1 * IN1 * HID + 0 * HID + o] + s11 * sW1[1 * IN1 * HID + 1 * HID + o] + s12 * sW1[1 * IN1 * HID + 2 * HID + o];
        acc[o] += s20 * sW1[2 * IN1 * HID + 0 * HID + o] + s21 * sW1[2 * IN1 * HID + 1 * HID + o] + s22 * sW1[2 * IN1 * HID + 2 * HID + o];
    }

    float hv[HID];
#pragma unroll
    for (int o = 0; o < HID; ++o) hv[o] = fmaxf(acc[o], 0.0f);

    for (int r = 0; r < RELS; ++r) {
        float o8[OUT2];
#pragma unroll
        for (int o = 0; o < OUT2; ++o) o8[o] = 0.f;
        const float* w = sW2 + r * HID * OUT2;
#pragma unroll
        for (int i = 0; i < HID; ++i)
#pragma unroll
            for (int o = 0; o < OUT2; ++o) o8[o] += hv[i] * w[i * OUT2 + o];
        float* dp = xw2 + ((size_t)r * N + n) * OUT2;
        float4 lo = {o8[0], o8[1], o8[2], o8[3]};
        float4 hi = {o8[4], o8[5], o8[6], o8[7]};
        *reinterpret_cast<float4*>(dp) = lo;
        *reinterpret_cast<float4*>(dp + 4) = hi;
    }
    {
        float o8[OUT2];
#pragma unroll
        for (int o = 0; o < OUT2; ++o) o8[o] = 0.f;
#pragma unroll
        for (int i = 0; i < HID; ++i)
#pragma unroll
            for (int o = 0; o < OUT2; ++o) o8[o] += hv[i] * sR2[i * OUT2 + o];
        float* dp = hroot + (size_t)n * OUT2;
        float4 lo = {o8[0], o8[1], o8[2], o8[3]};
        float4 hi = {o8[4], o8[5], o8[6], o8[7]};
        *reinterpret_cast<float4*>(dp) = lo;
        *reinterpret_cast<float4*>(dp + 4) = hi;
    }
}

// ---------------- layer2 fused ----------------
__global__ void k_layer2(const int* __restrict__ off_g, const unsigned* __restrict__ csr,
                         const float* __restrict__ xw2, const float* __restrict__ hroot,
                         const float* __restrict__ bias2, float* __restrict__ out, int N) {
    __shared__ float sB2[OUT2];
    for (int i = threadIdx.x; i < OUT2; i += blockDim.x) sB2[i] = bias2[i];
    __syncthreads();
    int n = blockIdx.x * blockDim.x + threadIdx.x;
    if (n >= N) return;

    int a = off_g[n], bnd = off_g[n + 1];
    float c0 = 0.f, c1 = 0.f, c2 = 0.f;
    for (int e = a; e < bnd; ++e) {
        int ty = csr[e] >> 18;
        c0 += (ty == 0) ? 1.f : 0.f;
        c1 += (ty == 1) ? 1.f : 0.f;
        c2 += (ty == 2) ? 1.f : 0.f;
    }
    float i0 = 1.0f / fmaxf(c0, 1.0f);
    float i1 = 1.0f / fmaxf(c1, 1.0f);
    float i2 = 1.0f / fmaxf(c2, 1.0f);

    float a0, a1, a2, a3, a4, a5, a6, a7;
    const float4* hp = reinterpret_cast<const float4*>(hroot + (size_t)n * OUT2);
    float4 h0 = hp[0], h1 = hp[1];
    a0 = sB2[0] + h0.x; a1 = sB2[1] + h0.y; a2 = sB2[2] + h0.z; a3 = sB2[3] + h0.w;
    a4 = sB2[4] + h1.x; a5 = sB2[5] + h1.y; a6 = sB2[6] + h1.z; a7 = sB2[7] + h1.w;

    for (int e = a; e < bnd; ++e) {
        unsigned v = csr[e];
        int ty = v >> 18;
        int s = v & 0x3FFFF;
        float w = (ty == 0) ? i0 : ((ty == 1) ? i1 : i2);
        const float4* p = reinterpret_cast<const float4*>(xw2 + ((size_t)ty * N + s) * OUT2);
        float4 v0 = p[0], v1 = p[1];
        a0 += w * v0.x; a1 += w * v0.y; a2 += w * v0.z; a3 += w * v0.w;
        a4 += w * v1.x; a5 += w * v1.y; a6 += w * v1.z; a7 += w * v1.w;
    }

    float mx = fmaxf(fmaxf(fmaxf(a0, a1), fmaxf(a2, a3)), fmaxf(fmaxf(a4, a5), fmaxf(a6, a7)));
    float s = expf(a0 - mx) + expf(a1 - mx) + expf(a2 - mx) + expf(a3 - mx)
            + expf(a4 - mx) + expf(a5 - mx) + expf(a6 - mx) + expf(a7 - mx);
    float lse = logf(s) + mx;
    float* op = out + (size_t)n * OUT2;
    float4 lo = {a0 - lse, a1 - lse, a2 - lse, a3 - lse};
    float4 hi = {a4 - lse, a5 - lse, a6 - lse, a7 - lse};
    *reinterpret_cast<float4*>(op) = lo;
    *reinterpret_cast<float4*>(op + 4) = hi;
}

extern "C" void kernel_launch(void* const* d_in, const int* in_sizes, int n_in,
                              void* d_out, int out_size, void* d_ws, size_t ws_size,
                              hipStream_t stream) {
    const float* x      = (const float*)d_in[0];
    const int*   eidx   = (const int*)d_in[1];
    const int*   etype  = (const int*)d_in[2];
    const float* basis1 = (const float*)d_in[3];
    const float* comp1  = (const float*)d_in[4];
    const float* root1  = (const float*)d_in[5];
    const float* bias1  = (const float*)d_in[6];
    const float* basis2 = (const float*)d_in[7];
    const float* comp2  = (const float*)d_in[8];
    const float* root2  = (const float*)d_in[9];
    const float* bias2  = (const float*)d_in[10];
    float* out = (float*)d_out;

    const int N = in_sizes[0] / IN1;
    const int E = in_sizes[2];
    const int B = in_sizes[3] / (IN1 * HID);

    const int* src = eidx;
    const int* dst = eidx + E;

    const int NBUCK = (N + BW - 1) / BW;        // 782
    const int NT    = (E + TILE - 1) / TILE;    // 782
    const int SLEN  = NBUCK * NT;               // 611,524

    // workspace layout (4-byte words), 16-word aligned chunks
    char* wsb = (char*)d_ws;
    size_t off_w = 0;
    auto alloc_w = [&](size_t words) {
        void* p = wsb + off_w * 4;
        off_w += (words + 15) & ~(size_t)15;
        return p;
    };
    int*      cnt   = (int*)alloc_w(SLEN);          // scanned in place -> off_e
    int*      bsums = (int*)alloc_w(1024);
    unsigned* part  = (unsigned*)alloc_w(E);        // later reused as xw2+hroot
    unsigned* csr   = (unsigned*)alloc_w(E);
    int*      offg  = (int*)alloc_w((size_t)NBUCK * BW + 16);
    float*    W1    = (float*)alloc_w(RELS * IN1 * HID);
    float*    W2    = (float*)alloc_w(RELS * HID * OUT2);
    float*    xw2   = (float*)part;                              // RELS*N*OUT2 floats
    float*    hroot = (float*)part + (size_t)RELS * N * OUT2;    // N*OUT2 floats

    k_compute_W<<<1, 384, 0, stream>>>(basis1, comp1, basis2, comp2, B, W1, W2);

    k_part_count<<<NT, TILE_T, 0, stream>>>(dst, cnt, E, NBUCK, NT);

    int NB = (SLEN + SCAN_TILE - 1) / SCAN_TILE;   // 299
    k_scan_block<<<NB, SCAN_BLOCK, 0, stream>>>(cnt, bsums, SLEN);
    k_scan_top<<<1, 1024, 0, stream>>>(bsums, NB);
    k_scan_add<<<(SLEN + 255) / 256, 256, 0, stream>>>(cnt, bsums, SLEN);

    k_part_scatter<<<NT, TILE_T, 0, stream>>>(src, dst, etype, cnt, part, E, NBUCK, NT);

    k_bucket_sort<<<NBUCK, BW, 0, stream>>>(cnt, part, csr, offg, E, NBUCK, NT);

    int grdN = (N + 255) / 256;
    k_layer1<<<grdN, 256, 0, stream>>>(x, offg, csr, W1, root1, bias1, W2, root2,
                                       xw2, hroot, N);
    k_layer2<<<grdN, 256, 0, stream>>>(offg, csr, xw2, hroot, bias2, out, N);
}

// Round 5
// 581.427 us; speedup vs baseline: 6.7589x; 1.2095x over previous
//
#include <hip/hip_runtime.h>

#define RELS 3
#define IN1  3
#define HID  16
#define OUT2 8

#define BW     256                 // dsts per bucket (== 1<<8)
#define BINS   1024                // (local_dst<<2)|type bins
#define MAXB   1024
#define TILE_T 256
#define TILE_I 32
#define TILE   (TILE_T * TILE_I)   // 8192 edges per partition block

#define SCAN_BLOCK 256
#define SCAN_ITEMS 8
#define SCAN_TILE  (SCAN_BLOCK * SCAN_ITEMS)   // 2048

#define CMAX 10240                 // LDS staging capacity in pass C (edges)

__device__ __forceinline__ float bf_lo(unsigned u) { return __uint_as_float(u << 16); }
__device__ __forceinline__ float bf_hi(unsigned u) { return __uint_as_float(u & 0xFFFF0000u); }
__device__ __forceinline__ unsigned pack_bf16(float a, float b) {
    unsigned ua = __float_as_uint(a);
    unsigned ub = __float_as_uint(b);
    ua = (ua + 0x7FFFu + ((ua >> 16) & 1u)) >> 16;
    ub = (ub + 0x7FFFu + ((ub >> 16) & 1u)) >> 16;
    return ua | (ub << 16);
}

// ---------------- W = comp @ basis (tiny) ----------------
__global__ void k_compute_W(const float* __restrict__ basis1, const float* __restrict__ comp1,
                            const float* __restrict__ basis2, const float* __restrict__ comp2,
                            int B, float* __restrict__ W1, float* __restrict__ W2) {
    int tid = threadIdx.x;
    if (tid < RELS * IN1 * HID) {
        int r = tid / (IN1 * HID), io = tid % (IN1 * HID);
        float acc = 0.f;
        for (int b = 0; b < B; ++b) acc += comp1[r * B + b] * basis1[b * IN1 * HID + io];
        W1[tid] = acc;
    }
    if (tid < RELS * HID * OUT2) {
        int r = tid / (HID * OUT2), io = tid % (HID * OUT2);
        float acc = 0.f;
        for (int b = 0; b < B; ++b) acc += comp2[r * B + b] * basis2[b * HID * OUT2 + io];
        W2[tid] = acc;
    }
}

// ---------------- pass A: per-block bucket histogram (LDS atomics only) ----------------
__global__ void k_part_count(const int* __restrict__ dst, int* __restrict__ cnt,
                             int E, int NBUCK, int NT) {
    __shared__ int hist[MAXB];
    for (int i = threadIdx.x; i < NBUCK; i += TILE_T) hist[i] = 0;
    __syncthreads();
    int base = blockIdx.x * TILE;
#pragma unroll 4
    for (int k = 0; k < TILE_I; ++k) {
        int e = base + k * TILE_T + threadIdx.x;
        if (e < E) atomicAdd(&hist[dst[e] >> 8], 1);
    }
    __syncthreads();
    for (int b = threadIdx.x; b < NBUCK; b += TILE_T)
        cnt[(size_t)b * NT + blockIdx.x] = hist[b];
}

// ---------------- scans ----------------
__global__ void k_scan_block(int* __restrict__ data, int* __restrict__ bsums, int S) {
    __shared__ int lds[SCAN_BLOCK];
    int base = blockIdx.x * SCAN_TILE + threadIdx.x * SCAN_ITEMS;
    int v[SCAN_ITEMS];
    int tot = 0;
#pragma unroll
    for (int k = 0; k < SCAN_ITEMS; ++k) {
        int i = base + k;
        v[k] = (i < S) ? data[i] : 0;
        tot += v[k];
    }
    lds[threadIdx.x] = tot;
    __syncthreads();
    for (int d = 1; d < SCAN_BLOCK; d <<= 1) {
        int val = lds[threadIdx.x];
        int add = (threadIdx.x >= d) ? lds[threadIdx.x - d] : 0;
        __syncthreads();
        lds[threadIdx.x] = val + add;
        __syncthreads();
    }
    int excl = (threadIdx.x == 0) ? 0 : lds[threadIdx.x - 1];
    if (threadIdx.x == SCAN_BLOCK - 1) bsums[blockIdx.x] = lds[SCAN_BLOCK - 1];
    int run = excl;
#pragma unroll
    for (int k = 0; k < SCAN_ITEMS; ++k) {
        int i = base + k;
        if (i < S) data[i] = run;
        run += v[k];
    }
}

__global__ void k_scan_top(int* __restrict__ bsums, int NB) {
    __shared__ int lds[1024];
    int t = threadIdx.x;
    lds[t] = (t < NB) ? bsums[t] : 0;
    __syncthreads();
    for (int d = 1; d < 1024; d <<= 1) {
        int val = lds[t];
        int add = (t >= d) ? lds[t - d] : 0;
        __syncthreads();
        lds[t] = val + add;
        __syncthreads();
    }
    int excl = (t == 0) ? 0 : lds[t - 1];
    if (t < NB) bsums[t] = excl;
}

__global__ void k_scan_add(int* __restrict__ data, const int* __restrict__ bsums, int S) {
    int i = blockIdx.x * blockDim.x + threadIdx.x;
    if (i < S) data[i] += bsums[i / SCAN_TILE];
}

// ---------------- pass B: scatter packed edges into bucket order (LDS atomics only) -----
__global__ void k_part_scatter(const int* __restrict__ src, const int* __restrict__ dst,
                               const int* __restrict__ et, const int* __restrict__ off_e,
                               unsigned* __restrict__ part, int E, int NBUCK, int NT) {
    __shared__ int cursor[MAXB];
    for (int i = threadIdx.x; i < NBUCK; i += TILE_T)
        cursor[i] = off_e[(size_t)i * NT + blockIdx.x];
    __syncthreads();
    int base = blockIdx.x * TILE;
#pragma unroll 4
    for (int k = 0; k < TILE_I; ++k) {
        int e = base + k * TILE_T + threadIdx.x;
        if (e < E) {
            int d = dst[e];
            int b = d >> 8;
            int pos = atomicAdd(&cursor[b], 1);
            unsigned pk = ((unsigned)(d & 255) << 20) | ((unsigned)et[e] << 18) | (unsigned)src[e];
            part[pos] = pk;
        }
    }
}

// ---------------- pass C: per-bucket counting sort by (ldst,type) -> CSR + seg offsets ---
__global__ void k_bucket_sort(const int* __restrict__ off_e, const unsigned* __restrict__ part,
                              unsigned* __restrict__ csr, int* __restrict__ off_g,
                              int E, int NBUCK, int NT, int N) {
    __shared__ int cnt[BINS];
    __shared__ int tsum[BW];
    __shared__ int cur[BINS];
    __shared__ unsigned loc[CMAX];
    int b = blockIdx.x, t = threadIdx.x;
    int bs = off_e[(size_t)b * NT];
    int be = (b + 1 < NBUCK) ? off_e[(size_t)(b + 1) * NT] : E;
    int sz = be - bs;
#pragma unroll
    for (int j = 0; j < 4; ++j) cnt[t * 4 + j] = 0;
    __syncthreads();
    for (int i = t; i < sz; i += BW)
        atomicAdd(&cnt[part[bs + i] >> 18], 1);
    __syncthreads();
    int c0 = cnt[4 * t + 0], c1 = cnt[4 * t + 1], c2 = cnt[4 * t + 2], c3 = cnt[4 * t + 3];
    int p1 = c0, p2 = c0 + c1, p3 = c0 + c1 + c2;
    tsum[t] = p3 + c3;
    __syncthreads();
    for (int d = 1; d < BW; d <<= 1) {
        int val = tsum[t];
        int add = (t >= d) ? tsum[t - d] : 0;
        __syncthreads();
        tsum[t] = val + add;
        __syncthreads();
    }
    int excl = (t == 0) ? 0 : tsum[t - 1];
    cur[4 * t + 0] = excl;
    cur[4 * t + 1] = excl + p1;
    cur[4 * t + 2] = excl + p2;
    cur[4 * t + 3] = excl + p3;
    int n = b * BW + t;
    if (n < N) {
        off_g[(size_t)n * 3 + 0] = bs + excl;
        off_g[(size_t)n * 3 + 1] = bs + excl + p1;
        off_g[(size_t)n * 3 + 2] = bs + excl + p2;
    } else if (n == N) {
        off_g[(size_t)N * 3] = bs + excl;
    }
    if (b == NBUCK - 1 && t == BW - 1) off_g[(size_t)N * 3] = E;
    __syncthreads();
    if (sz <= CMAX) {
        for (int i = t; i < sz; i += BW) {
            unsigned v = part[bs + i];
            int p = atomicAdd(&cur[v >> 18], 1);
            loc[p] = v & 0x3FFFF;
        }
        __syncthreads();
        for (int i = t; i < sz; i += BW) csr[bs + i] = loc[i];
    } else {
        for (int i = t; i < sz; i += BW) {
            unsigned v = part[bs + i];
            int p = atomicAdd(&cur[v >> 18], 1);
            csr[bs + p] = v & 0x3FFFF;
        }
    }
}

// ---------------- layer1: gather mean(x) per (r,n) -> h (bf16) ----------------
__global__ void k_layer1(const float* __restrict__ x, const int* __restrict__ off_g,
                         const unsigned* __restrict__ csr,
                         const float* __restrict__ W1, const float* __restrict__ root1,
                         const float* __restrict__ bias1,
                         unsigned* __restrict__ hq, int N) {
    __shared__ float sW1[RELS * IN1 * HID];
    __shared__ float sR1[IN1 * HID];
    __shared__ float sB1[HID];
    for (int i = threadIdx.x; i < RELS * IN1 * HID; i += blockDim.x) sW1[i] = W1[i];
    for (int i = threadIdx.x; i < IN1 * HID; i += blockDim.x) sR1[i] = root1[i];
    for (int i = threadIdx.x; i < HID; i += blockDim.x) sB1[i] = bias1[i];
    __syncthreads();
    int n = blockIdx.x * blockDim.x + threadIdx.x;
    if (n >= N) return;

    float acc[HID];
    float xv0 = x[3 * n + 0], xv1 = x[3 * n + 1], xv2 = x[3 * n + 2];
#pragma unroll
    for (int o = 0; o < HID; ++o)
        acc[o] = sB1[o] + xv0 * sR1[0 * HID + o] + xv1 * sR1[1 * HID + o] + xv2 * sR1[2 * HID + o];

    size_t base = (size_t)n * 3;
    for (int r = 0; r < RELS; ++r) {
        int a = off_g[base + r], bnd = off_g[base + r + 1];
        float s0 = 0.f, s1 = 0.f, s2 = 0.f;
        for (int e = a; e < bnd; ++e) {
            int s = csr[e];
            s0 += x[3 * s + 0];
            s1 += x[3 * s + 1];
            s2 += x[3 * s + 2];
        }
        float inv = 1.0f / fmaxf((float)(bnd - a), 1.0f);
        s0 *= inv; s1 *= inv; s2 *= inv;
        const float* w = sW1 + r * IN1 * HID;
#pragma unroll
        for (int o = 0; o < HID; ++o)
            acc[o] += s0 * w[0 * HID + o] + s1 * w[1 * HID + o] + s2 * w[2 * HID + o];
    }

    unsigned q[8];
#pragma unroll
    for (int j = 0; j < 8; ++j)
        q[j] = pack_bf16(fmaxf(acc[2 * j], 0.f), fmaxf(acc[2 * j + 1], 0.f));
    uint4* hp = reinterpret_cast<uint4*>(hq + (size_t)n * 8);
    hp[0] = make_uint4(q[0], q[1], q[2], q[3]);
    hp[1] = make_uint4(q[4], q[5], q[6], q[7]);
}

// ---------------- layer2a: per (r,n) segment: mean(h[src]) @ W2[r] -> partial ----------
__global__ void k_layer2a(const int* __restrict__ off_g, const unsigned* __restrict__ csr,
                          const unsigned* __restrict__ hq, const float* __restrict__ W2,
                          float* __restrict__ partial, int N) {
    __shared__ float sW2[RELS * HID * OUT2];
    for (int i = threadIdx.x; i < RELS * HID * OUT2; i += blockDim.x) sW2[i] = W2[i];
    __syncthreads();
    int seg = blockIdx.x * blockDim.x + threadIdx.x;
    if (seg >= 3 * N) return;
    int r = seg % 3;
    int a = off_g[seg], bnd = off_g[seg + 1];

    float s[HID];
#pragma unroll
    for (int i = 0; i < HID; ++i) s[i] = 0.f;
    for (int e = a; e < bnd; ++e) {
        unsigned srcn = csr[e];
        const uint4* hp = reinterpret_cast<const uint4*>(hq + (size_t)srcn * 8);
        uint4 q0 = hp[0], q1 = hp[1];
        s[0]  += bf_lo(q0.x); s[1]  += bf_hi(q0.x);
        s[2]  += bf_lo(q0.y); s[3]  += bf_hi(q0.y);
        s[4]  += bf_lo(q0.z); s[5]  += bf_hi(q0.z);
        s[6]  += bf_lo(q0.w); s[7]  += bf_hi(q0.w);
        s[8]  += bf_lo(q1.x); s[9]  += bf_hi(q1.x);
        s[10] += bf_lo(q1.y); s[11] += bf_hi(q1.y);
        s[12] += bf_lo(q1.z); s[13] += bf_hi(q1.z);
        s[14] += bf_lo(q1.w); s[15] += bf_hi(q1.w);
    }
    float inv = 1.0f / fmaxf((float)(bnd - a), 1.0f);
    const float* w = sW2 + r * HID * OUT2;
    float o8[OUT2];
#pragma unroll
    for (int o = 0; o < OUT2; ++o) o8[o] = 0.f;
#pragma unroll
    for (int i = 0; i < HID; ++i) {
        float sv = s[i] * inv;
#pragma unroll
        for (int o = 0; o < OUT2; ++o) o8[o] += sv * w[i * OUT2 + o];
    }
    float* dp = partial + (size_t)seg * OUT2;
    float4 lo = {o8[0], o8[1], o8[2], o8[3]};
    float4 hi = {o8[4], o8[5], o8[6], o8[7]};
    *reinterpret_cast<float4*>(dp) = lo;
    *reinterpret_cast<float4*>(dp + 4) = hi;
}

// ---------------- layer2b: partials + h@root2 + bias2 -> log_softmax ----------------
__global__ void k_layer2b(const unsigned* __restrict__ hq, const float* __restrict__ partial,
                          const float* __restrict__ root2, const float* __restrict__ bias2,
                          float* __restrict__ out, int N) {
    __shared__ float sR2[HID * OUT2];
    __shared__ float sB2[OUT2];
    for (int i = threadIdx.x; i < HID * OUT2; i += blockDim.x) sR2[i] = root2[i];
    for (int i = threadIdx.x; i < OUT2; i += blockDim.x) sB2[i] = bias2[i];
    __syncthreads();
    int n = blockIdx.x * blockDim.x + threadIdx.x;
    if (n >= N) return;

    float acc[OUT2];
    const float4* pp = reinterpret_cast<const float4*>(partial + (size_t)n * 3 * OUT2);
    float4 p0 = pp[0], p1 = pp[1], p2 = pp[2], p3 = pp[3], p4 = pp[4], p5 = pp[5];
    acc[0] = sB2[0] + p0.x + p2.x + p4.x;
    acc[1] = sB2[1] + p0.y + p2.y + p4.y;
    acc[2] = sB2[2] + p0.z + p2.z + p4.z;
    acc[3] = sB2[3] + p0.w + p2.w + p4.w;
    acc[4] = sB2[4] + p1.x + p3.x + p5.x;
    acc[5] = sB2[5] + p1.y + p3.y + p5.y;
    acc[6] = sB2[6] + p1.z + p3.z + p5.z;
    acc[7] = sB2[7] + p1.w + p3.w + p5.w;

    const uint4* hp = reinterpret_cast<const uint4*>(hq + (size_t)n * 8);
    uint4 q0 = hp[0], q1 = hp[1];
    float hv[HID] = {
        bf_lo(q0.x), bf_hi(q0.x), bf_lo(q0.y), bf_hi(q0.y),
        bf_lo(q0.z), bf_hi(q0.z), bf_lo(q0.w), bf_hi(q0.w),
        bf_lo(q1.x), bf_hi(q1.x), bf_lo(q1.y), bf_hi(q1.y),
        bf_lo(q1.z), bf_hi(q1.z), bf_lo(q1.w), bf_hi(q1.w)
    };
#pragma unroll
    for (int i = 0; i < HID; ++i)
#pragma unroll
        for (int o = 0; o < OUT2; ++o) acc[o] += hv[i] * sR2[i * OUT2 + o];

    float mx = acc[0];
#pragma unroll
    for (int o = 1; o < OUT2; ++o) mx = fmaxf(mx, acc[o]);
    float ssum = 0.f;
#pragma unroll
    for (int o = 0; o < OUT2; ++o) ssum += expf(acc[o] - mx);
    float lse = logf(ssum) + mx;
    float* op = out + (size_t)n * OUT2;
    float4 lo = {acc[0] - lse, acc[1] - lse, acc[2] - lse, acc[3] - lse};
    float4 hi = {acc[4] - lse, acc[5] - lse, acc[6] - lse, acc[7] - lse};
    *reinterpret_cast<float4*>(op) = lo;
    *reinterpret_cast<float4*>(op + 4) = hi;
}

extern "C" void kernel_launch(void* const* d_in, const int* in_sizes, int n_in,
                              void* d_out, int out_size, void* d_ws, size_t ws_size,
                              hipStream_t stream) {
    const float* x      = (const float*)d_in[0];
    const int*   eidx   = (const int*)d_in[1];
    const int*   etype  = (const int*)d_in[2];
    const float* basis1 = (const float*)d_in[3];
    const float* comp1  = (const float*)d_in[4];
    const float* root1  = (const float*)d_in[5];
    const float* bias1  = (const float*)d_in[6];
    const float* basis2 = (const float*)d_in[7];
    const float* comp2  = (const float*)d_in[8];
    const float* root2  = (const float*)d_in[9];
    const float* bias2  = (const float*)d_in[10];
    float* out = (float*)d_out;

    const int N = in_sizes[0] / IN1;
    const int E = in_sizes[2];
    const int B = in_sizes[3] / (IN1 * HID);

    const int* src = eidx;
    const int* dst = eidx + E;

    const int NBUCK = (N + BW - 1) / BW;        // 782
    const int NT    = (E + TILE - 1) / TILE;    // 782
    const int SLEN  = NBUCK * NT;

    char* wsb = (char*)d_ws;
    size_t off_w = 0;
    auto alloc_w = [&](size_t words) {
        void* p = wsb + off_w * 4;
        off_w += (words + 15) & ~(size_t)15;
        return p;
    };
    int*      cnt   = (int*)alloc_w(SLEN);          // scanned in place -> off_e
    int*      bsums = (int*)alloc_w(1024);
    unsigned* part  = (unsigned*)alloc_w(E);        // reused as partial after pass C
    unsigned* csr   = (unsigned*)alloc_w(E);
    int*      offg  = (int*)alloc_w((size_t)N * 3 + 16);
    float*    W1    = (float*)alloc_w(RELS * IN1 * HID);
    float*    W2    = (float*)alloc_w(RELS * HID * OUT2);
    unsigned* hq    = (unsigned*)alloc_w((size_t)N * 8);   // h in bf16, 16 per node
    float*    partial = (float*)part;                       // [3N][8] floats (19.2MB<=25.6MB)

    k_compute_W<<<1, 384, 0, stream>>>(basis1, comp1, basis2, comp2, B, W1, W2);

    k_part_count<<<NT, TILE_T, 0, stream>>>(dst, cnt, E, NBUCK, NT);

    int NB = (SLEN + SCAN_TILE - 1) / SCAN_TILE;
    k_scan_block<<<NB, SCAN_BLOCK, 0, stream>>>(cnt, bsums, SLEN);
    k_scan_top<<<1, 1024, 0, stream>>>(bsums, NB);
    k_scan_add<<<(SLEN + 255) / 256, 256, 0, stream>>>(cnt, bsums, SLEN);

    k_part_scatter<<<NT, TILE_T, 0, stream>>>(src, dst, etype, cnt, part, E, NBUCK, NT);

    k_bucket_sort<<<NBUCK, BW, 0, stream>>>(cnt, part, csr, offg, E, NBUCK, NT, N);

    int grdN = (N + 255) / 256;
    k_layer1<<<grdN, 256, 0, stream>>>(x, offg, csr, W1, root1, bias1, hq, N);

    int grdS = (3 * N + 255) / 256;
    k_layer2a<<<grdS, 256, 0, stream>>>(offg, csr, hq, W2, partial, N);

    k_layer2b<<<grdN, 256, 0, stream>>>(hq, partial, root2, bias2, out, N);
}

// Round 6
// 520.632 us; speedup vs baseline: 7.5481x; 1.1168x over previous
//
#include <hip/hip_runtime.h>

#define RELS 3
#define IN1  3
#define HID  16
#define OUT2 8

#define BW     256                 // dsts per bucket (== 1<<8)
#define BINS   1024                // (local_dst<<2)|type bins
#define MAXB   1024
#define TILE_T 256
#define TILE_I 32
#define TILE   (TILE_T * TILE_I)   // 8192 edges per partition block

#define SCAN_BLOCK 256
#define SCAN_ITEMS 8
#define SCAN_TILE  (SCAN_BLOCK * SCAN_ITEMS)   // 2048

#define CMAX 10240                 // LDS staging capacity in pass C (edges)

__device__ __forceinline__ float bf_lo(unsigned u) { return __uint_as_float(u << 16); }
__device__ __forceinline__ float bf_hi(unsigned u) { return __uint_as_float(u & 0xFFFF0000u); }
__device__ __forceinline__ unsigned pack_bf16(float a, float b) {
    unsigned ua = __float_as_uint(a);
    unsigned ub = __float_as_uint(b);
    ua = (ua + 0x7FFFu + ((ua >> 16) & 1u)) >> 16;
    ub = (ub + 0x7FFFu + ((ub >> 16) & 1u)) >> 16;
    return ua | (ub << 16);
}

// ---------------- W = comp @ basis (tiny) ----------------
__global__ void k_compute_W(const float* __restrict__ basis1, const float* __restrict__ comp1,
                            const float* __restrict__ basis2, const float* __restrict__ comp2,
                            int B, float* __restrict__ W1, float* __restrict__ W2) {
    int tid = threadIdx.x;
    if (tid < RELS * IN1 * HID) {
        int r = tid / (IN1 * HID), io = tid % (IN1 * HID);
        float acc = 0.f;
        for (int b = 0; b < B; ++b) acc += comp1[r * B + b] * basis1[b * IN1 * HID + io];
        W1[tid] = acc;
    }
    if (tid < RELS * HID * OUT2) {
        int r = tid / (HID * OUT2), io = tid % (HID * OUT2);
        float acc = 0.f;
        for (int b = 0; b < B; ++b) acc += comp2[r * B + b] * basis2[b * HID * OUT2 + io];
        W2[tid] = acc;
    }
}

// ---------------- pass A: per-block bucket histogram (LDS atomics only) ----------------
__global__ void k_part_count(const int* __restrict__ dst, int* __restrict__ cnt,
                             int E, int NBUCK, int NT) {
    __shared__ int hist[MAXB];
    for (int i = threadIdx.x; i < NBUCK; i += TILE_T) hist[i] = 0;
    __syncthreads();
    int base = blockIdx.x * TILE;
#pragma unroll 4
    for (int k = 0; k < TILE_I; ++k) {
        int e = base + k * TILE_T + threadIdx.x;
        if (e < E) atomicAdd(&hist[dst[e] >> 8], 1);
    }
    __syncthreads();
    for (int b = threadIdx.x; b < NBUCK; b += TILE_T)
        cnt[(size_t)b * NT + blockIdx.x] = hist[b];
}

// ---------------- scans ----------------
__global__ void k_scan_block(int* __restrict__ data, int* __restrict__ bsums, int S) {
    __shared__ int lds[SCAN_BLOCK];
    int base = blockIdx.x * SCAN_TILE + threadIdx.x * SCAN_ITEMS;
    int v[SCAN_ITEMS];
    int tot = 0;
#pragma unroll
    for (int k = 0; k < SCAN_ITEMS; ++k) {
        int i = base + k;
        v[k] = (i < S) ? data[i] : 0;
        tot += v[k];
    }
    lds[threadIdx.x] = tot;
    __syncthreads();
    for (int d = 1; d < SCAN_BLOCK; d <<= 1) {
        int val = lds[threadIdx.x];
        int add = (threadIdx.x >= d) ? lds[threadIdx.x - d] : 0;
        __syncthreads();
        lds[threadIdx.x] = val + add;
        __syncthreads();
    }
    int excl = (threadIdx.x == 0) ? 0 : lds[threadIdx.x - 1];
    if (threadIdx.x == SCAN_BLOCK - 1) bsums[blockIdx.x] = lds[SCAN_BLOCK - 1];
    int run = excl;
#pragma unroll
    for (int k = 0; k < SCAN_ITEMS; ++k) {
        int i = base + k;
        if (i < S) data[i] = run;
        run += v[k];
    }
}

__global__ void k_scan_top(int* __restrict__ bsums, int NB) {
    __shared__ int lds[1024];
    int t = threadIdx.x;
    lds[t] = (t < NB) ? bsums[t] : 0;
    __syncthreads();
    for (int d = 1; d < 1024; d <<= 1) {
        int val = lds[t];
        int add = (t >= d) ? lds[t - d] : 0;
        __syncthreads();
        lds[t] = val + add;
        __syncthreads();
    }
    int excl = (t == 0) ? 0 : lds[t - 1];
    if (t < NB) bsums[t] = excl;
}

__global__ void k_scan_add(int* __restrict__ data, const int* __restrict__ bsums, int S) {
    int i = blockIdx.x * blockDim.x + threadIdx.x;
    if (i < S) data[i] += bsums[i / SCAN_TILE];
}

// ---------------- pass B: block-local counting sort by bucket, coalesced flush ----------
__global__ void k_part_scatter(const int* __restrict__ src, const int* __restrict__ dst,
                               const int* __restrict__ et, const int* __restrict__ off_e,
                               unsigned* __restrict__ part, int E, int NBUCK, int NT) {
    __shared__ int cnt[MAXB];             // counts, then reused as local cursor
    __shared__ int bscan[TILE_T];
    __shared__ int base_l[MAXB];
    __shared__ int gbase[MAXB];
    __shared__ unsigned loc[TILE];
    __shared__ unsigned short bid[TILE];
    int t = threadIdx.x;
    int blk = blockIdx.x;
    for (int i = t; i < NBUCK; i += TILE_T) cnt[i] = 0;
    __syncthreads();
    int base = blk * TILE;
    int sz = min(TILE, E - base);
    // pass 1: count buckets
#pragma unroll 4
    for (int k = 0; k < TILE_I; ++k) {
        int e = base + k * TILE_T + t;
        if (e < E) atomicAdd(&cnt[dst[e] >> 8], 1);
    }
    __syncthreads();
    // exclusive scan over NBUCK bins (4 bins/thread)
    int c[4];
    int tot = 0;
#pragma unroll
    for (int j = 0; j < 4; ++j) {
        int b = t * 4 + j;
        c[j] = (b < NBUCK) ? cnt[b] : 0;
        tot += c[j];
    }
    bscan[t] = tot;
    __syncthreads();
    for (int d = 1; d < TILE_T; d <<= 1) {
        int val = bscan[t];
        int add = (t >= d) ? bscan[t - d] : 0;
        __syncthreads();
        bscan[t] = val + add;
        __syncthreads();
    }
    int run = (t == 0) ? 0 : bscan[t - 1];
#pragma unroll
    for (int j = 0; j < 4; ++j) {
        int b = t * 4 + j;
        if (b < NBUCK) { base_l[b] = run; cnt[b] = run; }  // cnt becomes cursor
        run += c[j];
    }
    for (int i = t; i < NBUCK; i += TILE_T)
        gbase[i] = off_e[(size_t)i * NT + blk];
    __syncthreads();
    // pass 2: place packed edges into LDS, bucket-grouped
#pragma unroll 4
    for (int k = 0; k < TILE_I; ++k) {
        int e = base + k * TILE_T + t;
        if (e < E) {
            int d = dst[e];
            int b = d >> 8;
            int slot = atomicAdd(&cnt[b], 1);
            loc[slot] = ((unsigned)(d & 255) << 20) | ((unsigned)et[e] << 18) | (unsigned)src[e];
            bid[slot] = (unsigned short)b;
        }
    }
    __syncthreads();
    // flush: consecutive threads -> consecutive global addresses within each run
    for (int i = t; i < sz; i += TILE_T) {
        int b = bid[i];
        part[gbase[b] + (i - base_l[b])] = loc[i];
    }
}

// ---------------- pass C: per-bucket counting sort by (ldst,type) -> CSR + seg offsets ---
__global__ void k_bucket_sort(const int* __restrict__ off_e, const unsigned* __restrict__ part,
                              unsigned* __restrict__ csr, int* __restrict__ off_g,
                              int E, int NBUCK, int NT, int N) {
    __shared__ int cnt[BINS];
    __shared__ int tsum[BW];
    __shared__ int cur[BINS];
    __shared__ unsigned loc[CMAX];
    int b = blockIdx.x, t = threadIdx.x;
    int bs = off_e[(size_t)b * NT];
    int be = (b + 1 < NBUCK) ? off_e[(size_t)(b + 1) * NT] : E;
    int sz = be - bs;
#pragma unroll
    for (int j = 0; j < 4; ++j) cnt[t * 4 + j] = 0;
    __syncthreads();
    for (int i = t; i < sz; i += BW)
        atomicAdd(&cnt[part[bs + i] >> 18], 1);
    __syncthreads();
    int c0 = cnt[4 * t + 0], c1 = cnt[4 * t + 1], c2 = cnt[4 * t + 2], c3 = cnt[4 * t + 3];
    int p1 = c0, p2 = c0 + c1, p3 = c0 + c1 + c2;
    tsum[t] = p3 + c3;
    __syncthreads();
    for (int d = 1; d < BW; d <<= 1) {
        int val = tsum[t];
        int add = (t >= d) ? tsum[t - d] : 0;
        __syncthreads();
        tsum[t] = val + add;
        __syncthreads();
    }
    int excl = (t == 0) ? 0 : tsum[t - 1];
    cur[4 * t + 0] = excl;
    cur[4 * t + 1] = excl + p1;
    cur[4 * t + 2] = excl + p2;
    cur[4 * t + 3] = excl + p3;
    int n = b * BW + t;
    if (n < N) {
        off_g[(size_t)n * 3 + 0] = bs + excl;
        off_g[(size_t)n * 3 + 1] = bs + excl + p1;
        off_g[(size_t)n * 3 + 2] = bs + excl + p2;
    } else if (n == N) {
        off_g[(size_t)N * 3] = bs + excl;
    }
    if (b == NBUCK - 1 && t == BW - 1) off_g[(size_t)N * 3] = E;
    __syncthreads();
    if (sz <= CMAX) {
        for (int i = t; i < sz; i += BW) {
            unsigned v = part[bs + i];
            int p = atomicAdd(&cur[v >> 18], 1);
            loc[p] = v & 0x3FFFF;
        }
        __syncthreads();
        for (int i = t; i < sz; i += BW) csr[bs + i] = loc[i];
    } else {
        for (int i = t; i < sz; i += BW) {
            unsigned v = part[bs + i];
            int p = atomicAdd(&cur[v >> 18], 1);
            csr[bs + p] = v & 0x3FFFF;
        }
    }
}

// ---------------- layer1: gather mean(x) per (r,n) -> h (bf16) ----------------
__global__ void k_layer1(const float* __restrict__ x, const int* __restrict__ off_g,
                         const unsigned* __restrict__ csr,
                         const float* __restrict__ W1, const float* __restrict__ root1,
                         const float* __restrict__ bias1,
                         unsigned* __restrict__ hq, int N) {
    __shared__ float sW1[RELS * IN1 * HID];
    __shared__ float sR1[IN1 * HID];
    __shared__ float sB1[HID];
    for (int i = threadIdx.x; i < RELS * IN1 * HID; i += blockDim.x) sW1[i] = W1[i];
    for (int i = threadIdx.x; i < IN1 * HID; i += blockDim.x) sR1[i] = root1[i];
    for (int i = threadIdx.x; i < HID; i += blockDim.x) sB1[i] = bias1[i];
    __syncthreads();
    int n = blockIdx.x * blockDim.x + threadIdx.x;
    if (n >= N) return;

    float acc[HID];
    float xv0 = x[3 * n + 0], xv1 = x[3 * n + 1], xv2 = x[3 * n + 2];
#pragma unroll
    for (int o = 0; o < HID; ++o)
        acc[o] = sB1[o] + xv0 * sR1[0 * HID + o] + xv1 * sR1[1 * HID + o] + xv2 * sR1[2 * HID + o];

    size_t base = (size_t)n * 3;
    for (int r = 0; r < RELS; ++r) {
        int a = off_g[base + r], bnd = off_g[base + r + 1];
        float s0 = 0.f, s1 = 0.f, s2 = 0.f;
        for (int e = a; e < bnd; ++e) {
            int s = csr[e];
            s0 += x[3 * s + 0];
            s1 += x[3 * s + 1];
            s2 += x[3 * s + 2];
        }
        float inv = 1.0f / fmaxf((float)(bnd - a), 1.0f);
        s0 *= inv; s1 *= inv; s2 *= inv;
        const float* w = sW1 + r * IN1 * HID;
#pragma unroll
        for (int o = 0; o < HID; ++o)
            acc[o] += s0 * w[0 * HID + o] + s1 * w[1 * HID + o] + s2 * w[2 * HID + o];
    }

    unsigned q[8];
#pragma unroll
    for (int j = 0; j < 8; ++j)
        q[j] = pack_bf16(fmaxf(acc[2 * j], 0.f), fmaxf(acc[2 * j + 1], 0.f));
    uint4* hp = reinterpret_cast<uint4*>(hq + (size_t)n * 8);
    hp[0] = make_uint4(q[0], q[1], q[2], q[3]);
    hp[1] = make_uint4(q[4], q[5], q[6], q[7]);
}

// ---------------- layer2a: per (r,n) segment: mean(h[src]) @ W2[r] -> partial ----------
__global__ void k_layer2a(const int* __restrict__ off_g, const unsigned* __restrict__ csr,
                          const unsigned* __restrict__ hq, const float* __restrict__ W2,
                          float* __restrict__ partial, int N) {
    __shared__ float sW2[RELS * HID * OUT2];
    for (int i = threadIdx.x; i < RELS * HID * OUT2; i += blockDim.x) sW2[i] = W2[i];
    __syncthreads();
    int seg = blockIdx.x * blockDim.x + threadIdx.x;
    if (seg >= 3 * N) return;
    int r = seg % 3;
    int a = off_g[seg], bnd = off_g[seg + 1];

    float s[HID];
#pragma unroll
    for (int i = 0; i < HID; ++i) s[i] = 0.f;
    for (int e = a; e < bnd; ++e) {
        unsigned srcn = csr[e];
        const uint4* hp = reinterpret_cast<const uint4*>(hq + (size_t)srcn * 8);
        uint4 q0 = hp[0], q1 = hp[1];
        s[0]  += bf_lo(q0.x); s[1]  += bf_hi(q0.x);
        s[2]  += bf_lo(q0.y); s[3]  += bf_hi(q0.y);
        s[4]  += bf_lo(q0.z); s[5]  += bf_hi(q0.z);
        s[6]  += bf_lo(q0.w); s[7]  += bf_hi(q0.w);
        s[8]  += bf_lo(q1.x); s[9]  += bf_hi(q1.x);
        s[10] += bf_lo(q1.y); s[11] += bf_hi(q1.y);
        s[12] += bf_lo(q1.z); s[13] += bf_hi(q1.z);
        s[14] += bf_lo(q1.w); s[15] += bf_hi(q1.w);
    }
    float inv = 1.0f / fmaxf((float)(bnd - a), 1.0f);
    const float* w = sW2 + r * HID * OUT2;
    float o8[OUT2];
#pragma unroll
    for (int o = 0; o < OUT2; ++o) o8[o] = 0.f;
#pragma unroll
    for (int i = 0; i < HID; ++i) {
        float sv = s[i] * inv;
#pragma unroll
        for (int o = 0; o < OUT2; ++o) o8[o] += sv * w[i * OUT2 + o];
    }
    float* dp = partial + (size_t)seg * OUT2;
    float4 lo = {o8[0], o8[1], o8[2], o8[3]};
    float4 hi = {o8[4], o8[5], o8[6], o8[7]};
    *reinterpret_cast<float4*>(dp) = lo;
    *reinterpret_cast<float4*>(dp + 4) = hi;
}

// ---------------- layer2b: partials + h@root2 + bias2 -> log_softmax ----------------
__global__ void k_layer2b(const unsigned* __restrict__ hq, const float* __restrict__ partial,
                          const float* __restrict__ root2, const float* __restrict__ bias2,
                          float* __restrict__ out, int N) {
    __shared__ float sR2[HID * OUT2];
    __shared__ float sB2[OUT2];
    for (int i = threadIdx.x; i < HID * OUT2; i += blockDim.x) sR2[i] = root2[i];
    for (int i = threadIdx.x; i < OUT2; i += blockDim.x) sB2[i] = bias2[i];
    __syncthreads();
    int n = blockIdx.x * blockDim.x + threadIdx.x;
    if (n >= N) return;

    float acc[OUT2];
    const float4* pp = reinterpret_cast<const float4*>(partial + (size_t)n * 3 * OUT2);
    float4 p0 = pp[0], p1 = pp[1], p2 = pp[2], p3 = pp[3], p4 = pp[4], p5 = pp[5];
    acc[0] = sB2[0] + p0.x + p2.x + p4.x;
    acc[1] = sB2[1] + p0.y + p2.y + p4.y;
    acc[2] = sB2[2] + p0.z + p2.z + p4.z;
    acc[3] = sB2[3] + p0.w + p2.w + p4.w;
    acc[4] = sB2[4] + p1.x + p3.x + p5.x;
    acc[5] = sB2[5] + p1.y + p3.y + p5.y;
    acc[6] = sB2[6] + p1.z + p3.z + p5.z;
    acc[7] = sB2[7] + p1.w + p3.w + p5.w;

    const uint4* hp = reinterpret_cast<const uint4*>(hq + (size_t)n * 8);
    uint4 q0 = hp[0], q1 = hp[1];
    float hv[HID] = {
        bf_lo(q0.x), bf_hi(q0.x), bf_lo(q0.y), bf_hi(q0.y),
        bf_lo(q0.z), bf_hi(q0.z), bf_lo(q0.w), bf_hi(q0.w),
        bf_lo(q1.x), bf_hi(q1.x), bf_lo(q1.y), bf_hi(q1.y),
        bf_lo(q1.z), bf_hi(q1.z), bf_lo(q1.w), bf_hi(q1.w)
    };
#pragma unroll
    for (int i = 0; i < HID; ++i)
#pragma unroll
        for (int o = 0; o < OUT2; ++o) acc[o] += hv[i] * sR2[i * OUT2 + o];

    float mx = acc[0];
#pragma unroll
    for (int o = 1; o < OUT2; ++o) mx = fmaxf(mx, acc[o]);
    float ssum = 0.f;
#pragma unroll
    for (int o = 0; o < OUT2; ++o) ssum += expf(acc[o] - mx);
    float lse = logf(ssum) + mx;
    float* op = out + (size_t)n * OUT2;
    float4 lo = {acc[0] - lse, acc[1] - lse, acc[2] - lse, acc[3] - lse};
    float4 hi = {acc[4] - lse, acc[5] - lse, acc[6] - lse, acc[7] - lse};
    *reinterpret_cast<float4*>(op) = lo;
    *reinterpret_cast<float4*>(op + 4) = hi;
}

extern "C" void kernel_launch(void* const* d_in, const int* in_sizes, int n_in,
                              void* d_out, int out_size, void* d_ws, size_t ws_size,
                              hipStream_t stream) {
    const float* x      = (const float*)d_in[0];
    const int*   eidx   = (const int*)d_in[1];
    const int*   etype  = (const int*)d_in[2];
    const float* basis1 = (const float*)d_in[3];
    const float* comp1  = (const float*)d_in[4];
    const float* root1  = (const float*)d_in[5];
    const float* bias1  = (const float*)d_in[6];
    const float* basis2 = (const float*)d_in[7];
    const float* comp2  = (const float*)d_in[8];
    const float* root2  = (const float*)d_in[9];
    const float* bias2  = (const float*)d_in[10];
    float* out = (float*)d_out;

    const int N = in_sizes[0] / IN1;
    const int E = in_sizes[2];
    const int B = in_sizes[3] / (IN1 * HID);

    const int* src = eidx;
    const int* dst = eidx + E;

    const int NBUCK = (N + BW - 1) / BW;        // 782
    const int NT    = (E + TILE - 1) / TILE;    // 782
    const int SLEN  = NBUCK * NT;

    char* wsb = (char*)d_ws;
    size_t off_w = 0;
    auto alloc_w = [&](size_t words) {
        void* p = wsb + off_w * 4;
        off_w += (words + 15) & ~(size_t)15;
        return p;
    };
    int*      cnt   = (int*)alloc_w(SLEN);          // scanned in place -> off_e
    int*      bsums = (int*)alloc_w(1024);
    unsigned* part  = (unsigned*)alloc_w(E);        // reused as partial after pass C
    unsigned* csr   = (unsigned*)alloc_w(E);
    int*      offg  = (int*)alloc_w((size_t)N * 3 + 16);
    float*    W1    = (float*)alloc_w(RELS * IN1 * HID);
    float*    W2    = (float*)alloc_w(RELS * HID * OUT2);
    unsigned* hq    = (unsigned*)alloc_w((size_t)N * 8);   // h in bf16, 16 per node
    float*    partial = (float*)part;                       // [3N][8] floats (19.2MB<=25.6MB)

    k_compute_W<<<1, 384, 0, stream>>>(basis1, comp1, basis2, comp2, B, W1, W2);

    k_part_count<<<NT, TILE_T, 0, stream>>>(dst, cnt, E, NBUCK, NT);

    int NB = (SLEN + SCAN_TILE - 1) / SCAN_TILE;
    k_scan_block<<<NB, SCAN_BLOCK, 0, stream>>>(cnt, bsums, SLEN);
    k_scan_top<<<1, 1024, 0, stream>>>(bsums, NB);
    k_scan_add<<<(SLEN + 255) / 256, 256, 0, stream>>>(cnt, bsums, SLEN);

    k_part_scatter<<<NT, TILE_T, 0, stream>>>(src, dst, etype, cnt, part, E, NBUCK, NT);

    k_bucket_sort<<<NBUCK, BW, 0, stream>>>(cnt, part, csr, offg, E, NBUCK, NT, N);

    int grdN = (N + 255) / 256;
    k_layer1<<<grdN, 256, 0, stream>>>(x, offg, csr, W1, root1, bias1, hq, N);

    int grdS = (3 * N + 255) / 256;
    k_layer2a<<<grdS, 256, 0, stream>>>(offg, csr, hq, W2, partial, N);

    k_layer2b<<<grdN, 256, 0, stream>>>(hq, partial, root2, bias2, out, N);
}

// Round 7
// 452.613 us; speedup vs baseline: 8.6824x; 1.1503x over previous
//
#include <hip/hip_runtime.h>

#define RELS 3
#define IN1  3
#define HID  16
#define OUT2 8

#define BW     256                 // dsts per bucket (== 1<<8)
#define BINS   1024                // (local_dst<<2)|type bins
#define MAXB   1024
#define TILE_T 256
#define TILE_I 32
#define TILE   (TILE_T * TILE_I)   // 8192 edges per partition block

#define SCAN_BLOCK 256
#define SCAN_ITEMS 8
#define SCAN_TILE  (SCAN_BLOCK * SCAN_ITEMS)   // 2048

#define CMAX 10240                 // LDS staging capacity in pass C (edges)

__device__ __forceinline__ float bf_lo(unsigned u) { return __uint_as_float(u << 16); }
__device__ __forceinline__ float bf_hi(unsigned u) { return __uint_as_float(u & 0xFFFF0000u); }
__device__ __forceinline__ unsigned pack_bf16(float a, float b) {
    unsigned ua = __float_as_uint(a);
    unsigned ub = __float_as_uint(b);
    ua = (ua + 0x7FFFu + ((ua >> 16) & 1u)) >> 16;
    ub = (ub + 0x7FFFu + ((ub >> 16) & 1u)) >> 16;
    return ua | (ub << 16);
}

// ---------------- W = comp @ basis (tiny) ----------------
__global__ void k_compute_W(const float* __restrict__ basis1, const float* __restrict__ comp1,
                            const float* __restrict__ basis2, const float* __restrict__ comp2,
                            int B, float* __restrict__ W1, float* __restrict__ W2) {
    int tid = threadIdx.x;
    if (tid < RELS * IN1 * HID) {
        int r = tid / (IN1 * HID), io = tid % (IN1 * HID);
        float acc = 0.f;
        for (int b = 0; b < B; ++b) acc += comp1[r * B + b] * basis1[b * IN1 * HID + io];
        W1[tid] = acc;
    }
    if (tid < RELS * HID * OUT2) {
        int r = tid / (HID * OUT2), io = tid % (HID * OUT2);
        float acc = 0.f;
        for (int b = 0; b < B; ++b) acc += comp2[r * B + b] * basis2[b * HID * OUT2 + io];
        W2[tid] = acc;
    }
}

// ---------------- pack x into bf16x3 (8B) ----------------
__global__ void k_pack_x(const float* __restrict__ x, uint2* __restrict__ xq, int N) {
    int n = blockIdx.x * blockDim.x + threadIdx.x;
    if (n >= N) return;
    float x0 = x[3 * n + 0], x1 = x[3 * n + 1], x2 = x[3 * n + 2];
    xq[n] = make_uint2(pack_bf16(x0, x1), pack_bf16(x2, 0.f));
}

// ---------------- pass A: per-block bucket histogram (LDS atomics only) ----------------
__global__ void k_part_count(const int* __restrict__ dst, int* __restrict__ cnt,
                             int E, int NBUCK, int NT) {
    __shared__ int hist[MAXB];
    for (int i = threadIdx.x; i < NBUCK; i += TILE_T) hist[i] = 0;
    __syncthreads();
    int base = blockIdx.x * TILE;
#pragma unroll 4
    for (int k = 0; k < TILE_I; ++k) {
        int e = base + k * TILE_T + threadIdx.x;
        if (e < E) atomicAdd(&hist[dst[e] >> 8], 1);
    }
    __syncthreads();
    for (int b = threadIdx.x; b < NBUCK; b += TILE_T)
        cnt[(size_t)b * NT + blockIdx.x] = hist[b];
}

// ---------------- scans ----------------
__global__ void k_scan_block(int* __restrict__ data, int* __restrict__ bsums, int S) {
    __shared__ int lds[SCAN_BLOCK];
    int base = blockIdx.x * SCAN_TILE + threadIdx.x * SCAN_ITEMS;
    int v[SCAN_ITEMS];
    int tot = 0;
#pragma unroll
    for (int k = 0; k < SCAN_ITEMS; ++k) {
        int i = base + k;
        v[k] = (i < S) ? data[i] : 0;
        tot += v[k];
    }
    lds[threadIdx.x] = tot;
    __syncthreads();
    for (int d = 1; d < SCAN_BLOCK; d <<= 1) {
        int val = lds[threadIdx.x];
        int add = (threadIdx.x >= d) ? lds[threadIdx.x - d] : 0;
        __syncthreads();
        lds[threadIdx.x] = val + add;
        __syncthreads();
    }
    int excl = (threadIdx.x == 0) ? 0 : lds[threadIdx.x - 1];
    if (threadIdx.x == SCAN_BLOCK - 1) bsums[blockIdx.x] = lds[SCAN_BLOCK - 1];
    int run = excl;
#pragma unroll
    for (int k = 0; k < SCAN_ITEMS; ++k) {
        int i = base + k;
        if (i < S) data[i] = run;
        run += v[k];
    }
}

__global__ void k_scan_top(int* __restrict__ bsums, int NB) {
    __shared__ int lds[1024];
    int t = threadIdx.x;
    lds[t] = (t < NB) ? bsums[t] : 0;
    __syncthreads();
    for (int d = 1; d < 1024; d <<= 1) {
        int val = lds[t];
        int add = (t >= d) ? lds[t - d] : 0;
        __syncthreads();
        lds[t] = val + add;
        __syncthreads();
    }
    int excl = (t == 0) ? 0 : lds[t - 1];
    if (t < NB) bsums[t] = excl;
}

__global__ void k_scan_add(int* __restrict__ data, const int* __restrict__ bsums, int S) {
    int i = blockIdx.x * blockDim.x + threadIdx.x;
    if (i < S) data[i] += bsums[i / SCAN_TILE];
}

// ---------------- pass B: block-local counting sort by bucket, coalesced flush ----------
__global__ void k_part_scatter(const int* __restrict__ src, const int* __restrict__ dst,
                               const int* __restrict__ et, const int* __restrict__ off_e,
                               unsigned* __restrict__ part, int E, int NBUCK, int NT) {
    __shared__ int cnt[MAXB];             // counts, then reused as local cursor
    __shared__ int bscan[TILE_T];
    __shared__ int base_l[MAXB];
    __shared__ int gbase[MAXB];
    __shared__ unsigned loc[TILE];
    __shared__ unsigned short bid[TILE];
    int t = threadIdx.x;
    int blk = blockIdx.x;
    for (int i = t; i < NBUCK; i += TILE_T) cnt[i] = 0;
    __syncthreads();
    int base = blk * TILE;
    int sz = min(TILE, E - base);
    // pass 1: count buckets
#pragma unroll 4
    for (int k = 0; k < TILE_I; ++k) {
        int e = base + k * TILE_T + t;
        if (e < E) atomicAdd(&cnt[dst[e] >> 8], 1);
    }
    __syncthreads();
    // exclusive scan over NBUCK bins (4 bins/thread)
    int c[4];
    int tot = 0;
#pragma unroll
    for (int j = 0; j < 4; ++j) {
        int b = t * 4 + j;
        c[j] = (b < NBUCK) ? cnt[b] : 0;
        tot += c[j];
    }
    bscan[t] = tot;
    __syncthreads();
    for (int d = 1; d < TILE_T; d <<= 1) {
        int val = bscan[t];
        int add = (t >= d) ? bscan[t - d] : 0;
        __syncthreads();
        bscan[t] = val + add;
        __syncthreads();
    }
    int run = (t == 0) ? 0 : bscan[t - 1];
#pragma unroll
    for (int j = 0; j < 4; ++j) {
        int b = t * 4 + j;
        if (b < NBUCK) { base_l[b] = run; cnt[b] = run; }  // cnt becomes cursor
        run += c[j];
    }
    for (int i = t; i < NBUCK; i += TILE_T)
        gbase[i] = off_e[(size_t)i * NT + blk];
    __syncthreads();
    // pass 2: place packed edges into LDS, bucket-grouped
#pragma unroll 4
    for (int k = 0; k < TILE_I; ++k) {
        int e = base + k * TILE_T + t;
        if (e < E) {
            int d = dst[e];
            int b = d >> 8;
            int slot = atomicAdd(&cnt[b], 1);
            loc[slot] = ((unsigned)(d & 255) << 20) | ((unsigned)et[e] << 18) | (unsigned)src[e];
            bid[slot] = (unsigned short)b;
        }
    }
    __syncthreads();
    // flush: consecutive threads -> consecutive global addresses within each run
    for (int i = t; i < sz; i += TILE_T) {
        int b = bid[i];
        part[gbase[b] + (i - base_l[b])] = loc[i];
    }
}

// ---------------- pass C: per-bucket counting sort by (ldst,type) -> CSR + seg offsets ---
__global__ void k_bucket_sort(const int* __restrict__ off_e, const unsigned* __restrict__ part,
                              unsigned* __restrict__ csr, int* __restrict__ off_g,
                              int E, int NBUCK, int NT, int N) {
    __shared__ int cnt[BINS];
    __shared__ int tsum[BW];
    __shared__ int cur[BINS];
    __shared__ unsigned loc[CMAX];
    int b = blockIdx.x, t = threadIdx.x;
    int bs = off_e[(size_t)b * NT];
    int be = (b + 1 < NBUCK) ? off_e[(size_t)(b + 1) * NT] : E;
    int sz = be - bs;
#pragma unroll
    for (int j = 0; j < 4; ++j) cnt[t * 4 + j] = 0;
    __syncthreads();
    for (int i = t; i < sz; i += BW)
        atomicAdd(&cnt[part[bs + i] >> 18], 1);
    __syncthreads();
    int c0 = cnt[4 * t + 0], c1 = cnt[4 * t + 1], c2 = cnt[4 * t + 2], c3 = cnt[4 * t + 3];
    int p1 = c0, p2 = c0 + c1, p3 = c0 + c1 + c2;
    tsum[t] = p3 + c3;
    __syncthreads();
    for (int d = 1; d < BW; d <<= 1) {
        int val = tsum[t];
        int add = (t >= d) ? tsum[t - d] : 0;
        __syncthreads();
        tsum[t] = val + add;
        __syncthreads();
    }
    int excl = (t == 0) ? 0 : tsum[t - 1];
    cur[4 * t + 0] = excl;
    cur[4 * t + 1] = excl + p1;
    cur[4 * t + 2] = excl + p2;
    cur[4 * t + 3] = excl + p3;
    int n = b * BW + t;
    if (n < N) {
        off_g[(size_t)n * 3 + 0] = bs + excl;
        off_g[(size_t)n * 3 + 1] = bs + excl + p1;
        off_g[(size_t)n * 3 + 2] = bs + excl + p2;
    } else if (n == N) {
        off_g[(size_t)N * 3] = bs + excl;
    }
    if (b == NBUCK - 1 && t == BW - 1) off_g[(size_t)N * 3] = E;
    __syncthreads();
    if (sz <= CMAX) {
        for (int i = t; i < sz; i += BW) {
            unsigned v = part[bs + i];
            int p = atomicAdd(&cur[v >> 18], 1);
            loc[p] = v & 0x3FFFF;
        }
        __syncthreads();
        for (int i = t; i < sz; i += BW) csr[bs + i] = loc[i];
    } else {
        for (int i = t; i < sz; i += BW) {
            unsigned v = part[bs + i];
            int p = atomicAdd(&cur[v >> 18], 1);
            csr[bs + p] = v & 0x3FFFF;
        }
    }
}

// ---------------- layer1a: per (r,n) segment: mean(xq[src]) -> mxq (bf16x3) ----------
__global__ void k_layer1a(const int* __restrict__ off_g, const unsigned* __restrict__ csr,
                          const uint2* __restrict__ xq, uint2* __restrict__ mxq, int NSEG) {
    int seg = blockIdx.x * blockDim.x + threadIdx.x;
    if (seg >= NSEG) return;
    int a = off_g[seg], b = off_g[seg + 1];
    float s0 = 0.f, s1 = 0.f, s2 = 0.f;
    for (int e = a; e < b; ++e) {
        uint2 v = xq[csr[e]];
        s0 += bf_lo(v.x);
        s1 += bf_hi(v.x);
        s2 += bf_lo(v.y);
    }
    float inv = 1.0f / fmaxf((float)(b - a), 1.0f);
    mxq[seg] = make_uint2(pack_bf16(s0 * inv, s1 * inv), pack_bf16(s2 * inv, 0.f));
}

// ---------------- layer1b: means @ W1 + x@root1 + bias -> relu -> hq (bf16) ----------
__global__ void k_layer1b(const float* __restrict__ x, const uint2* __restrict__ mxq,
                          const float* __restrict__ W1, const float* __restrict__ root1,
                          const float* __restrict__ bias1,
                          unsigned* __restrict__ hq, int N) {
    __shared__ float sW1[RELS * IN1 * HID];
    __shared__ float sR1[IN1 * HID];
    __shared__ float sB1[HID];
    for (int i = threadIdx.x; i < RELS * IN1 * HID; i += blockDim.x) sW1[i] = W1[i];
    for (int i = threadIdx.x; i < IN1 * HID; i += blockDim.x) sR1[i] = root1[i];
    for (int i = threadIdx.x; i < HID; i += blockDim.x) sB1[i] = bias1[i];
    __syncthreads();
    int n = blockIdx.x * blockDim.x + threadIdx.x;
    if (n >= N) return;

    float acc[HID];
    float xv0 = x[3 * n + 0], xv1 = x[3 * n + 1], xv2 = x[3 * n + 2];
#pragma unroll
    for (int o = 0; o < HID; ++o)
        acc[o] = sB1[o] + xv0 * sR1[0 * HID + o] + xv1 * sR1[1 * HID + o] + xv2 * sR1[2 * HID + o];

#pragma unroll
    for (int r = 0; r < RELS; ++r) {
        uint2 m = mxq[(size_t)n * 3 + r];
        float m0 = bf_lo(m.x), m1 = bf_hi(m.x), m2 = bf_lo(m.y);
        const float* w = sW1 + r * IN1 * HID;
#pragma unroll
        for (int o = 0; o < HID; ++o)
            acc[o] += m0 * w[0 * HID + o] + m1 * w[1 * HID + o] + m2 * w[2 * HID + o];
    }

    unsigned q[8];
#pragma unroll
    for (int j = 0; j < 8; ++j)
        q[j] = pack_bf16(fmaxf(acc[2 * j], 0.f), fmaxf(acc[2 * j + 1], 0.f));
    uint4* hp = reinterpret_cast<uint4*>(hq + (size_t)n * 8);
    hp[0] = make_uint4(q[0], q[1], q[2], q[3]);
    hp[1] = make_uint4(q[4], q[5], q[6], q[7]);
}

// ---------------- layer2a: per (r,n) segment: mean(h[src]) @ W2[r] -> partial ----------
__global__ void k_layer2a(const int* __restrict__ off_g, const unsigned* __restrict__ csr,
                          const unsigned* __restrict__ hq, const float* __restrict__ W2,
                          float* __restrict__ partial, int N) {
    __shared__ float sW2[RELS * HID * OUT2];
    for (int i = threadIdx.x; i < RELS * HID * OUT2; i += blockDim.x) sW2[i] = W2[i];
    __syncthreads();
    int seg = blockIdx.x * blockDim.x + threadIdx.x;
    if (seg >= 3 * N) return;
    int r = seg % 3;
    int a = off_g[seg], bnd = off_g[seg + 1];

    float s[HID];
#pragma unroll
    for (int i = 0; i < HID; ++i) s[i] = 0.f;
    for (int e = a; e < bnd; ++e) {
        unsigned srcn = csr[e];
        const uint4* hp = reinterpret_cast<const uint4*>(hq + (size_t)srcn * 8);
        uint4 q0 = hp[0], q1 = hp[1];
        s[0]  += bf_lo(q0.x); s[1]  += bf_hi(q0.x);
        s[2]  += bf_lo(q0.y); s[3]  += bf_hi(q0.y);
        s[4]  += bf_lo(q0.z); s[5]  += bf_hi(q0.z);
        s[6]  += bf_lo(q0.w); s[7]  += bf_hi(q0.w);
        s[8]  += bf_lo(q1.x); s[9]  += bf_hi(q1.x);
        s[10] += bf_lo(q1.y); s[11] += bf_hi(q1.y);
        s[12] += bf_lo(q1.z); s[13] += bf_hi(q1.z);
        s[14] += bf_lo(q1.w); s[15] += bf_hi(q1.w);
    }
    float inv = 1.0f / fmaxf((float)(bnd - a), 1.0f);
    const float* w = sW2 + r * HID * OUT2;
    float o8[OUT2];
#pragma unroll
    for (int o = 0; o < OUT2; ++o) o8[o] = 0.f;
#pragma unroll
    for (int i = 0; i < HID; ++i) {
        float sv = s[i] * inv;
#pragma unroll
        for (int o = 0; o < OUT2; ++o) o8[o] += sv * w[i * OUT2 + o];
    }
    float* dp = partial + (size_t)seg * OUT2;
    float4 lo = {o8[0], o8[1], o8[2], o8[3]};
    float4 hi = {o8[4], o8[5], o8[6], o8[7]};
    *reinterpret_cast<float4*>(dp) = lo;
    *reinterpret_cast<float4*>(dp + 4) = hi;
}

// ---------------- layer2b: partials + h@root2 + bias2 -> log_softmax ----------------
__global__ void k_layer2b(const unsigned* __restrict__ hq, const float* __restrict__ partial,
                          const float* __restrict__ root2, const float* __restrict__ bias2,
                          float* __restrict__ out, int N) {
    __shared__ float sR2[HID * OUT2];
    __shared__ float sB2[OUT2];
    for (int i = threadIdx.x; i < HID * OUT2; i += blockDim.x) sR2[i] = root2[i];
    for (int i = threadIdx.x; i < OUT2; i += blockDim.x) sB2[i] = bias2[i];
    __syncthreads();
    int n = blockIdx.x * blockDim.x + threadIdx.x;
    if (n >= N) return;

    float acc[OUT2];
    const float4* pp = reinterpret_cast<const float4*>(partial + (size_t)n * 3 * OUT2);
    float4 p0 = pp[0], p1 = pp[1], p2 = pp[2], p3 = pp[3], p4 = pp[4], p5 = pp[5];
    acc[0] = sB2[0] + p0.x + p2.x + p4.x;
    acc[1] = sB2[1] + p0.y + p2.y + p4.y;
    acc[2] = sB2[2] + p0.z + p2.z + p4.z;
    acc[3] = sB2[3] + p0.w + p2.w + p4.w;
    acc[4] = sB2[4] + p1.x + p3.x + p5.x;
    acc[5] = sB2[5] + p1.y + p3.y + p5.y;
    acc[6] = sB2[6] + p1.z + p3.z + p5.z;
    acc[7] = sB2[7] + p1.w + p3.w + p5.w;

    const uint4* hp = reinterpret_cast<const uint4*>(hq + (size_t)n * 8);
    uint4 q0 = hp[0], q1 = hp[1];
    float hv[HID] = {
        bf_lo(q0.x), bf_hi(q0.x), bf_lo(q0.y), bf_hi(q0.y),
        bf_lo(q0.z), bf_hi(q0.z), bf_lo(q0.w), bf_hi(q0.w),
        bf_lo(q1.x), bf_hi(q1.x), bf_lo(q1.y), bf_hi(q1.y),
        bf_lo(q1.z), bf_hi(q1.z), bf_lo(q1.w), bf_hi(q1.w)
    };
#pragma unroll
    for (int i = 0; i < HID; ++i)
#pragma unroll
        for (int o = 0; o < OUT2; ++o) acc[o] += hv[i] * sR2[i * OUT2 + o];

    float mx = acc[0];
#pragma unroll
    for (int o = 1; o < OUT2; ++o) mx = fmaxf(mx, acc[o]);
    float ssum = 0.f;
#pragma unroll
    for (int o = 0; o < OUT2; ++o) ssum += expf(acc[o] - mx);
    float lse = logf(ssum) + mx;
    float* op = out + (size_t)n * OUT2;
    float4 lo = {acc[0] - lse, acc[1] - lse, acc[2] - lse, acc[3] - lse};
    float4 hi = {acc[4] - lse, acc[5] - lse, acc[6] - lse, acc[7] - lse};
    *reinterpret_cast<float4*>(op) = lo;
    *reinterpret_cast<float4*>(op + 4) = hi;
}

extern "C" void kernel_launch(void* const* d_in, const int* in_sizes, int n_in,
                              void* d_out, int out_size, void* d_ws, size_t ws_size,
                              hipStream_t stream) {
    const float* x      = (const float*)d_in[0];
    const int*   eidx   = (const int*)d_in[1];
    const int*   etype  = (const int*)d_in[2];
    const float* basis1 = (const float*)d_in[3];
    const float* comp1  = (const float*)d_in[4];
    const float* root1  = (const float*)d_in[5];
    const float* bias1  = (const float*)d_in[6];
    const float* basis2 = (const float*)d_in[7];
    const float* comp2  = (const float*)d_in[8];
    const float* root2  = (const float*)d_in[9];
    const float* bias2  = (const float*)d_in[10];
    float* out = (float*)d_out;

    const int N = in_sizes[0] / IN1;
    const int E = in_sizes[2];
    const int B = in_sizes[3] / (IN1 * HID);

    const int* src = eidx;
    const int* dst = eidx + E;

    const int NBUCK = (N + BW - 1) / BW;        // 782
    const int NT    = (E + TILE - 1) / TILE;    // 782
    const int SLEN  = NBUCK * NT;

    char* wsb = (char*)d_ws;
    size_t off_w = 0;
    auto alloc_w = [&](size_t words) {
        void* p = wsb + off_w * 4;
        off_w += (words + 15) & ~(size_t)15;
        return p;
    };
    int*      cnt   = (int*)alloc_w(SLEN);          // scanned in place -> off_e
    int*      bsums = (int*)alloc_w(1024);
    unsigned* part  = (unsigned*)alloc_w(E);        // reused: partial / mxq after pass C
    unsigned* csr   = (unsigned*)alloc_w(E);
    int*      offg  = (int*)alloc_w((size_t)N * 3 + 16);
    float*    W1    = (float*)alloc_w(RELS * IN1 * HID);
    float*    W2    = (float*)alloc_w(RELS * HID * OUT2);
    unsigned* hq    = (unsigned*)alloc_w((size_t)N * 8);   // h in bf16, 16 per node
    uint2*    xq    = (uint2*)alloc_w((size_t)N * 2);      // x in bf16x3, 8B per node
    float*    partial = (float*)part;                       // [3N][8] floats (19.2MB<=25.6MB)
    uint2*    mxq   = (uint2*)(part + (size_t)RELS * N * OUT2);  // 3N uint2 in part tail (live
                                                                 // after bucket_sort, before layer2a)

    k_compute_W<<<1, 384, 0, stream>>>(basis1, comp1, basis2, comp2, B, W1, W2);

    int grdN = (N + 255) / 256;
    k_pack_x<<<grdN, 256, 0, stream>>>(x, xq, N);

    k_part_count<<<NT, TILE_T, 0, stream>>>(dst, cnt, E, NBUCK, NT);

    int NB = (SLEN + SCAN_TILE - 1) / SCAN_TILE;
    k_scan_block<<<NB, SCAN_BLOCK, 0, stream>>>(cnt, bsums, SLEN);
    k_scan_top<<<1, 1024, 0, stream>>>(bsums, NB);
    k_scan_add<<<(SLEN + 255) / 256, 256, 0, stream>>>(cnt, bsums, SLEN);

    k_part_scatter<<<NT, TILE_T, 0, stream>>>(src, dst, etype, cnt, part, E, NBUCK, NT);

    k_bucket_sort<<<NBUCK, BW, 0, stream>>>(cnt, part, csr, offg, E, NBUCK, NT, N);

    int NSEG = 3 * N;
    int grdS = (NSEG + 255) / 256;
    k_layer1a<<<grdS, 256, 0, stream>>>(offg, csr, xq, mxq, NSEG);
    k_layer1b<<<grdN, 256, 0, stream>>>(x, mxq, W1, root1, bias1, hq, N);

    k_layer2a<<<grdS, 256, 0, stream>>>(offg, csr, hq, W2, partial, N);

    k_layer2b<<<grdN, 256, 0, stream>>>(hq, partial, root2, bias2, out, N);
}

// Round 12
// 406.635 us; speedup vs baseline: 9.6642x; 1.1131x over previous
//
#include <hip/hip_runtime.h>

#define RELS 3
#define IN1  3
#define HID  16
#define OUT2 8

#define BW     256                 // dsts per bucket (== 1<<8)
#define BINS   1024                // (local_dst<<2)|type bins
#define MAXB   1024
#define TILE_T 256
#define TILE_I 32
#define TILE   (TILE_T * TILE_I)   // 8192 edges per partition block

#define SCAN_BLOCK 256
#define SCAN_ITEMS 8
#define SCAN_TILE  (SCAN_BLOCK * SCAN_ITEMS)   // 2048

#define CMAX 10240                 // LDS staging capacity in pass C (edges)

__device__ __forceinline__ float bf_lo(unsigned u) { return __uint_as_float(u << 16); }
__device__ __forceinline__ float bf_hi(unsigned u) { return __uint_as_float(u & 0xFFFF0000u); }
__device__ __forceinline__ unsigned pack_bf16(float a, float b) {
    unsigned ua = __float_as_uint(a);
    unsigned ub = __float_as_uint(b);
    ua = (ua + 0x7FFFu + ((ua >> 16) & 1u)) >> 16;
    ub = (ub + 0x7FFFu + ((ub >> 16) & 1u)) >> 16;
    return ua | (ub << 16);
}

// fp8 e4m3 (bias 7), nonnegative inputs only (post-ReLU), subnormal-preserving
__device__ __forceinline__ unsigned enc_fp8(float f) {
    if (f < 0.015625f) return (unsigned)(f * 512.0f + 0.5f);   // subnormal: u = round(f*2^9)
    unsigned bits = __float_as_uint(f);
    unsigned r = bits + 0x7FFFFu + ((bits >> 20) & 1u);        // RNE to 3 mantissa bits
    unsigned u = (r >> 20) - 960u;
    return u > 127u ? 127u : u;
}
__device__ __forceinline__ float dec_fp8(unsigned u) {
    return (u >= 8u) ? __uint_as_float((u + 960u) << 20) : (float)u * 0.001953125f;
}

// accumulate a 16-byte fp8 row into s[16]
__device__ __forceinline__ void acc_fp8row(uint4 q, float* s) {
    unsigned w;
#pragma unroll
    for (int j = 0; j < 4; ++j) {
        w = (j == 0) ? q.x : (j == 1) ? q.y : (j == 2) ? q.z : q.w;
#pragma unroll
        for (int b = 0; b < 4; ++b)
            s[j * 4 + b] += dec_fp8((w >> (8 * b)) & 0xFFu);
    }
}

// ---------------- W = comp @ basis (tiny) ----------------
__global__ void k_compute_W(const float* __restrict__ basis1, const float* __restrict__ comp1,
                            const float* __restrict__ basis2, const float* __restrict__ comp2,
                            int B, float* __restrict__ W1, float* __restrict__ W2) {
    int tid = threadIdx.x;
    if (tid < RELS * IN1 * HID) {
        int r = tid / (IN1 * HID), io = tid % (IN1 * HID);
        float acc = 0.f;
        for (int b = 0; b < B; ++b) acc += comp1[r * B + b] * basis1[b * IN1 * HID + io];
        W1[tid] = acc;
    }
    if (tid < RELS * HID * OUT2) {
        int r = tid / (HID * OUT2), io = tid % (HID * OUT2);
        float acc = 0.f;
        for (int b = 0; b < B; ++b) acc += comp2[r * B + b] * basis2[b * HID * OUT2 + io];
        W2[tid] = acc;
    }
}

// ---------------- pack x into bf16x3 (8B) ----------------
__global__ void k_pack_x(const float* __restrict__ x, uint2* __restrict__ xq, int N) {
    int n = blockIdx.x * blockDim.x + threadIdx.x;
    if (n >= N) return;
    float x0 = x[3 * n + 0], x1 = x[3 * n + 1], x2 = x[3 * n + 2];
    xq[n] = make_uint2(pack_bf16(x0, x1), pack_bf16(x2, 0.f));
}

// ---------------- pass A: per-block bucket histogram (LDS atomics only) ----------------
__global__ void k_part_count(const int* __restrict__ dst, int* __restrict__ cnt,
                             int E, int NBUCK, int NT) {
    __shared__ int hist[MAXB];
    for (int i = threadIdx.x; i < NBUCK; i += TILE_T) hist[i] = 0;
    __syncthreads();
    int base = blockIdx.x * TILE;
#pragma unroll 4
    for (int k = 0; k < TILE_I; ++k) {
        int e = base + k * TILE_T + threadIdx.x;
        if (e < E) atomicAdd(&hist[dst[e] >> 8], 1);
    }
    __syncthreads();
    for (int b = threadIdx.x; b < NBUCK; b += TILE_T)
        cnt[(size_t)b * NT + blockIdx.x] = hist[b];
}

// ---------------- scans ----------------
__global__ void k_scan_block(int* __restrict__ data, int* __restrict__ bsums, int S) {
    __shared__ int lds[SCAN_BLOCK];
    int base = blockIdx.x * SCAN_TILE + threadIdx.x * SCAN_ITEMS;
    int v[SCAN_ITEMS];
    int tot = 0;
#pragma unroll
    for (int k = 0; k < SCAN_ITEMS; ++k) {
        int i = base + k;
        v[k] = (i < S) ? data[i] : 0;
        tot += v[k];
    }
    lds[threadIdx.x] = tot;
    __syncthreads();
    for (int d = 1; d < SCAN_BLOCK; d <<= 1) {
        int val = lds[threadIdx.x];
        int add = (threadIdx.x >= d) ? lds[threadIdx.x - d] : 0;
        __syncthreads();
        lds[threadIdx.x] = val + add;
        __syncthreads();
    }
    int excl = (threadIdx.x == 0) ? 0 : lds[threadIdx.x - 1];
    if (threadIdx.x == SCAN_BLOCK - 1) bsums[blockIdx.x] = lds[SCAN_BLOCK - 1];
    int run = excl;
#pragma unroll
    for (int k = 0; k < SCAN_ITEMS; ++k) {
        int i = base + k;
        if (i < S) data[i] = run;
        run += v[k];
    }
}

__global__ void k_scan_top(int* __restrict__ bsums, int NB) {
    __shared__ int lds[1024];
    int t = threadIdx.x;
    lds[t] = (t < NB) ? bsums[t] : 0;
    __syncthreads();
    for (int d = 1; d < 1024; d <<= 1) {
        int val = lds[t];
        int add = (t >= d) ? lds[t - d] : 0;
        __syncthreads();
        lds[t] = val + add;
        __syncthreads();
    }
    int excl = (t == 0) ? 0 : lds[t - 1];
    if (t < NB) bsums[t] = excl;
}

__global__ void k_scan_add(int* __restrict__ data, const int* __restrict__ bsums, int S) {
    int i = blockIdx.x * blockDim.x + threadIdx.x;
    if (i < S) data[i] += bsums[i / SCAN_TILE];
}

// ---------------- pass B: block-local counting sort by bucket, coalesced flush ----------
__global__ void k_part_scatter(const int* __restrict__ src, const int* __restrict__ dst,
                               const int* __restrict__ et, const int* __restrict__ off_e,
                               unsigned* __restrict__ part, int E, int NBUCK, int NT) {
    __shared__ int cnt[MAXB];             // counts, then reused as local cursor
    __shared__ int bscan[TILE_T];
    __shared__ int base_l[MAXB];
    __shared__ int gbase[MAXB];
    __shared__ unsigned loc[TILE];
    __shared__ unsigned short bid[TILE];
    int t = threadIdx.x;
    int blk = blockIdx.x;
    for (int i = t; i < NBUCK; i += TILE_T) cnt[i] = 0;
    __syncthreads();
    int base = blk * TILE;
    int sz = min(TILE, E - base);
    // pass 1: count buckets
#pragma unroll 4
    for (int k = 0; k < TILE_I; ++k) {
        int e = base + k * TILE_T + t;
        if (e < E) atomicAdd(&cnt[dst[e] >> 8], 1);
    }
    __syncthreads();
    // exclusive scan over NBUCK bins (4 bins/thread)
    int c[4];
    int tot = 0;
#pragma unroll
    for (int j = 0; j < 4; ++j) {
        int b = t * 4 + j;
        c[j] = (b < NBUCK) ? cnt[b] : 0;
        tot += c[j];
    }
    bscan[t] = tot;
    __syncthreads();
    for (int d = 1; d < TILE_T; d <<= 1) {
        int val = bscan[t];
        int add = (t >= d) ? bscan[t - d] : 0;
        __syncthreads();
        bscan[t] = val + add;
        __syncthreads();
    }
    int run = (t == 0) ? 0 : bscan[t - 1];
#pragma unroll
    for (int j = 0; j < 4; ++j) {
        int b = t * 4 + j;
        if (b < NBUCK) { base_l[b] = run; cnt[b] = run; }  // cnt becomes cursor
        run += c[j];
    }
    for (int i = t; i < NBUCK; i += TILE_T)
        gbase[i] = off_e[(size_t)i * NT + blk];
    __syncthreads();
    // pass 2: place packed edges into LDS, bucket-grouped
#pragma unroll 4
    for (int k = 0; k < TILE_I; ++k) {
        int e = base + k * TILE_T + t;
        if (e < E) {
            int d = dst[e];
            int b = d >> 8;
            int slot = atomicAdd(&cnt[b], 1);
            loc[slot] = ((unsigned)(d & 255) << 20) | ((unsigned)et[e] << 18) | (unsigned)src[e];
            bid[slot] = (unsigned short)b;
        }
    }
    __syncthreads();
    // flush: consecutive threads -> consecutive global addresses within each run
    for (int i = t; i < sz; i += TILE_T) {
        int b = bid[i];
        part[gbase[b] + (i - base_l[b])] = loc[i];
    }
}

// ---------------- pass C: per-bucket counting sort by (ldst,type) -> CSR + seg offsets ---
__global__ void k_bucket_sort(const int* __restrict__ off_e, const unsigned* __restrict__ part,
                              unsigned* __restrict__ csr, int* __restrict__ off_g,
                              int E, int NBUCK, int NT, int N) {
    __shared__ int cnt[BINS];
    __shared__ int tsum[BW];
    __shared__ int cur[BINS];
    __shared__ unsigned loc[CMAX];
    int b = blockIdx.x, t = threadIdx.x;
    int bs = off_e[(size_t)b * NT];
    int be = (b + 1 < NBUCK) ? off_e[(size_t)(b + 1) * NT] : E;
    int sz = be - bs;
#pragma unroll
    for (int j = 0; j < 4; ++j) cnt[t * 4 + j] = 0;
    __syncthreads();
    for (int i = t; i < sz; i += BW)
        atomicAdd(&cnt[part[bs + i] >> 18], 1);
    __syncthreads();
    int c0 = cnt[4 * t + 0], c1 = cnt[4 * t + 1], c2 = cnt[4 * t + 2], c3 = cnt[4 * t + 3];
    int p1 = c0, p2 = c0 + c1, p3 = c0 + c1 + c2;
    tsum[t] = p3 + c3;
    __syncthreads();
    for (int d = 1; d < BW; d <<= 1) {
        int val = tsum[t];
        int add = (t >= d) ? tsum[t - d] : 0;
        __syncthreads();
        tsum[t] = val + add;
        __syncthreads();
    }
    int excl = (t == 0) ? 0 : tsum[t - 1];
    cur[4 * t + 0] = excl;
    cur[4 * t + 1] = excl + p1;
    cur[4 * t + 2] = excl + p2;
    cur[4 * t + 3] = excl + p3;
    int n = b * BW + t;
    if (n < N) {
        off_g[(size_t)n * 3 + 0] = bs + excl;
        off_g[(size_t)n * 3 + 1] = bs + excl + p1;
        off_g[(size_t)n * 3 + 2] = bs + excl + p2;
    } else if (n == N) {
        off_g[(size_t)N * 3] = bs + excl;
    }
    if (b == NBUCK - 1 && t == BW - 1) off_g[(size_t)N * 3] = E;
    __syncthreads();
    if (sz <= CMAX) {
        for (int i = t; i < sz; i += BW) {
            unsigned v = part[bs + i];
            int p = atomicAdd(&cur[v >> 18], 1);
            loc[p] = v & 0x3FFFF;
        }
        __syncthreads();
        for (int i = t; i < sz; i += BW) csr[bs + i] = loc[i];
    } else {
        for (int i = t; i < sz; i += BW) {
            unsigned v = part[bs + i];
            int p = atomicAdd(&cur[v >> 18], 1);
            csr[bs + p] = v & 0x3FFFF;
        }
    }
}

// ---------------- layer1a: per (r,n) segment: mean(xq[src]) -> mxq (bf16x3) ----------
__global__ void k_layer1a(const int* __restrict__ off_g, const unsigned* __restrict__ csr,
                          const uint2* __restrict__ xq, unsigned* __restrict__ mxq, int NSEG) {
    int seg = blockIdx.x * blockDim.x + threadIdx.x;
    if (seg >= NSEG) return;
    int a = off_g[seg], b = off_g[seg + 1];
    float s0 = 0.f, s1 = 0.f, s2 = 0.f;
    int e = a;
    for (; e + 4 <= b; e += 4) {
        unsigned i0 = __builtin_nontemporal_load(csr + e);
        unsigned i1 = __builtin_nontemporal_load(csr + e + 1);
        unsigned i2 = __builtin_nontemporal_load(csr + e + 2);
        unsigned i3 = __builtin_nontemporal_load(csr + e + 3);
        uint2 v0 = xq[i0], v1 = xq[i1], v2 = xq[i2], v3 = xq[i3];
        s0 += bf_lo(v0.x) + bf_lo(v1.x) + bf_lo(v2.x) + bf_lo(v3.x);
        s1 += bf_hi(v0.x) + bf_hi(v1.x) + bf_hi(v2.x) + bf_hi(v3.x);
        s2 += bf_lo(v0.y) + bf_lo(v1.y) + bf_lo(v2.y) + bf_lo(v3.y);
    }
    for (; e < b; ++e) {
        uint2 v = xq[__builtin_nontemporal_load(csr + e)];
        s0 += bf_lo(v.x);
        s1 += bf_hi(v.x);
        s2 += bf_lo(v.y);
    }
    float inv = 1.0f / fmaxf((float)(b - a), 1.0f);
    unsigned* p = mxq + (size_t)seg * 2;
    __builtin_nontemporal_store(pack_bf16(s0 * inv, s1 * inv), p);
    __builtin_nontemporal_store(pack_bf16(s2 * inv, 0.f), p + 1);
}

// ---------------- layer1b: means @ W1 + x@root1 + bias -> relu -> hq (bf16) + hq8 (fp8) --
__global__ void k_layer1b(const float* __restrict__ x, const unsigned* __restrict__ mxq,
                          const float* __restrict__ W1, const float* __restrict__ root1,
                          const float* __restrict__ bias1,
                          unsigned* __restrict__ hq, uint4* __restrict__ hq8, int N) {
    __shared__ float sW1[RELS * IN1 * HID];
    __shared__ float sR1[IN1 * HID];
    __shared__ float sB1[HID];
    for (int i = threadIdx.x; i < RELS * IN1 * HID; i += blockDim.x) sW1[i] = W1[i];
    for (int i = threadIdx.x; i < IN1 * HID; i += blockDim.x) sR1[i] = root1[i];
    for (int i = threadIdx.x; i < HID; i += blockDim.x) sB1[i] = bias1[i];
    __syncthreads();
    int n = blockIdx.x * blockDim.x + threadIdx.x;
    if (n >= N) return;

    float acc[HID];
    float xv0 = x[3 * n + 0], xv1 = x[3 * n + 1], xv2 = x[3 * n + 2];
#pragma unroll
    for (int o = 0; o < HID; ++o)
        acc[o] = sB1[o] + xv0 * sR1[0 * HID + o] + xv1 * sR1[1 * HID + o] + xv2 * sR1[2 * HID + o];

#pragma unroll
    for (int r = 0; r < RELS; ++r) {
        unsigned m0w = mxq[((size_t)n * 3 + r) * 2];
        unsigned m1w = mxq[((size_t)n * 3 + r) * 2 + 1];
        float m0 = bf_lo(m0w), m1 = bf_hi(m0w), m2 = bf_lo(m1w);
        const float* w = sW1 + r * IN1 * HID;
#pragma unroll
        for (int o = 0; o < HID; ++o)
            acc[o] += m0 * w[0 * HID + o] + m1 * w[1 * HID + o] + m2 * w[2 * HID + o];
    }

    float hv[HID];
#pragma unroll
    for (int o = 0; o < HID; ++o) hv[o] = fmaxf(acc[o], 0.f);

    unsigned q[8];
#pragma unroll
    for (int j = 0; j < 8; ++j) q[j] = pack_bf16(hv[2 * j], hv[2 * j + 1]);
    uint4* hp = reinterpret_cast<uint4*>(hq + (size_t)n * 8);
    hp[0] = make_uint4(q[0], q[1], q[2], q[3]);
    hp[1] = make_uint4(q[4], q[5], q[6], q[7]);

    unsigned f8[4];
#pragma unroll
    for (int j = 0; j < 4; ++j) {
        f8[j] = enc_fp8(hv[4 * j + 0])
              | (enc_fp8(hv[4 * j + 1]) << 8)
              | (enc_fp8(hv[4 * j + 2]) << 16)
              | (enc_fp8(hv[4 * j + 3]) << 24);
    }
    hq8[n] = make_uint4(f8[0], f8[1], f8[2], f8[3]);
}

// ---------------- layer2a: per (r,n) segment: mean(h8[src]) @ W2[r] -> partialq (bf16) --
__global__ void k_layer2a(const int* __restrict__ off_g, const unsigned* __restrict__ csr,
                          const uint4* __restrict__ hq8, const float* __restrict__ W2,
                          unsigned* __restrict__ partialq, int N) {
    __shared__ float sW2[RELS * HID * OUT2];
    for (int i = threadIdx.x; i < RELS * HID * OUT2; i += blockDim.x) sW2[i] = W2[i];
    __syncthreads();
    int seg = blockIdx.x * blockDim.x + threadIdx.x;
    if (seg >= 3 * N) return;
    int r = seg % 3;
    int a = off_g[seg], bnd = off_g[seg + 1];

    float s[HID];
#pragma unroll
    for (int i = 0; i < HID; ++i) s[i] = 0.f;
    int e = a;
    for (; e + 4 <= bnd; e += 4) {
        unsigned i0 = __builtin_nontemporal_load(csr + e);
        unsigned i1 = __builtin_nontemporal_load(csr + e + 1);
        unsigned i2 = __builtin_nontemporal_load(csr + e + 2);
        unsigned i3 = __builtin_nontemporal_load(csr + e + 3);
        uint4 q0 = hq8[i0], q1 = hq8[i1], q2 = hq8[i2], q3 = hq8[i3];
        acc_fp8row(q0, s);
        acc_fp8row(q1, s);
        acc_fp8row(q2, s);
        acc_fp8row(q3, s);
    }
    for (; e < bnd; ++e) {
        uint4 q = hq8[__builtin_nontemporal_load(csr + e)];
        acc_fp8row(q, s);
    }
    float inv = 1.0f / fmaxf((float)(bnd - a), 1.0f);
    float o8[OUT2];
#pragma unroll
    for (int o = 0; o < OUT2; ++o) o8[o] = 0.f;
    const float* w = sW2 + r * HID * OUT2;
#pragma unroll
    for (int i = 0; i < HID; ++i) {
        float sv = s[i] * inv;
#pragma unroll
        for (int o = 0; o < OUT2; ++o) o8[o] += sv * w[i * OUT2 + o];
    }
    unsigned* p = partialq + (size_t)seg * 4;
    __builtin_nontemporal_store(pack_bf16(o8[0], o8[1]), p);
    __builtin_nontemporal_store(pack_bf16(o8[2], o8[3]), p + 1);
    __builtin_nontemporal_store(pack_bf16(o8[4], o8[5]), p + 2);
    __builtin_nontemporal_store(pack_bf16(o8[6], o8[7]), p + 3);
}

// ---------------- layer2b: partials + h@root2 + bias2 -> log_softmax ----------------
__global__ void k_layer2b(const unsigned* __restrict__ hq, const uint4* __restrict__ partialq,
                          const float* __restrict__ root2, const float* __restrict__ bias2,
                          float* __restrict__ out, int N) {
    __shared__ float sR2[HID * OUT2];
    __shared__ float sB2[OUT2];
    for (int i = threadIdx.x; i < HID * OUT2; i += blockDim.x) sR2[i] = root2[i];
    for (int i = threadIdx.x; i < OUT2; i += blockDim.x) sB2[i] = bias2[i];
    __syncthreads();
    int n = blockIdx.x * blockDim.x + threadIdx.x;
    if (n >= N) return;

    float acc[OUT2];
#pragma unroll
    for (int o = 0; o < OUT2; ++o) acc[o] = sB2[o];
#pragma unroll
    for (int r = 0; r < RELS; ++r) {
        uint4 P = partialq[(size_t)n * 3 + r];
        acc[0] += bf_lo(P.x); acc[1] += bf_hi(P.x);
        acc[2] += bf_lo(P.y); acc[3] += bf_hi(P.y);
        acc[4] += bf_lo(P.z); acc[5] += bf_hi(P.z);
        acc[6] += bf_lo(P.w); acc[7] += bf_hi(P.w);
    }

    const uint4* hp = reinterpret_cast<const uint4*>(hq + (size_t)n * 8);
    uint4 q0 = hp[0], q1 = hp[1];
    float hv[HID] = {
        bf_lo(q0.x), bf_hi(q0.x), bf_lo(q0.y), bf_hi(q0.y),
        bf_lo(q0.z), bf_hi(q0.z), bf_lo(q0.w), bf_hi(q0.w),
        bf_lo(q1.x), bf_hi(q1.x), bf_lo(q1.y), bf_hi(q1.y),
        bf_lo(q1.z), bf_hi(q1.z), bf_lo(q1.w), bf_hi(q1.w)
    };
#pragma unroll
    for (int i = 0; i < HID; ++i)
#pragma unroll
        for (int o = 0; o < OUT2; ++o) acc[o] += hv[i] * sR2[i * OUT2 + o];

    float mx = acc[0];
#pragma unroll
    for (int o = 1; o < OUT2; ++o) mx = fmaxf(mx, acc[o]);
    float ssum = 0.f;
#pragma unroll
    for (int o = 0; o < OUT2; ++o) ssum += expf(acc[o] - mx);
    float lse = logf(ssum) + mx;
    float* op = out + (size_t)n * OUT2;
    float4 lo = {acc[0] - lse, acc[1] - lse, acc[2] - lse, acc[3] - lse};
    float4 hi = {acc[4] - lse, acc[5] - lse, acc[6] - lse, acc[7] - lse};
    *reinterpret_cast<float4*>(op) = lo;
    *reinterpret_cast<float4*>(op + 4) = hi;
}

extern "C" void kernel_launch(void* const* d_in, const int* in_sizes, int n_in,
                              void* d_out, int out_size, void* d_ws, size_t ws_size,
                              hipStream_t stream) {
    const float* x      = (const float*)d_in[0];
    const int*   eidx   = (const int*)d_in[1];
    const int*   etype  = (const int*)d_in[2];
    const float* basis1 = (const float*)d_in[3];
    const float* comp1  = (const float*)d_in[4];
    const float* root1  = (const float*)d_in[5];
    const float* bias1  = (const float*)d_in[6];
    const float* basis2 = (const float*)d_in[7];
    const float* comp2  = (const float*)d_in[8];
    const float* root2  = (const float*)d_in[9];
    const float* bias2  = (const float*)d_in[10];
    float* out = (float*)d_out;

    const int N = in_sizes[0] / IN1;
    const int E = in_sizes[2];
    const int B = in_sizes[3] / (IN1 * HID);

    const int* src = eidx;
    const int* dst = eidx + E;

    const int NBUCK = (N + BW - 1) / BW;        // 782
    const int NT    = (E + TILE - 1) / TILE;    // 782
    const int SLEN  = NBUCK * NT;

    char* wsb = (char*)d_ws;
    size_t off_w = 0;
    auto alloc_w = [&](size_t words) {
        void* p = wsb + off_w * 4;
        off_w += (words + 15) & ~(size_t)15;
        return p;
    };
    int*      cnt   = (int*)alloc_w(SLEN);          // scanned in place -> off_e
    int*      bsums = (int*)alloc_w(1024);
    unsigned* part  = (unsigned*)alloc_w(E);        // reused after pass C (see below)
    unsigned* csr   = (unsigned*)alloc_w(E);
    int*      offg  = (int*)alloc_w((size_t)N * 3 + 16);
    float*    W1    = (float*)alloc_w(RELS * IN1 * HID);
    float*    W2    = (float*)alloc_w(RELS * HID * OUT2);
    unsigned* hq    = (unsigned*)alloc_w((size_t)N * 8);   // h in bf16, 32B per node
    uint2*    xq    = (uint2*)alloc_w((size_t)N * 2);      // x in bf16x3, 8B per node
    // aliases inside dead part[] (raw edges consumed by bucket_sort):
    //   partialq: 3N uint4 (bf16 partials)  @ part + 0       (12N words)
    //   mxq:      3N uint2 (bf16 means)     @ part + 12N     (6N words)
    //   hq8:      N  uint4 (fp8 h rows)     @ part + 18N     (4N words)   [22N <= E]
    unsigned* partialq = part;
    unsigned* mxq      = part + (size_t)12 * N;
    uint4*    hq8      = (uint4*)(part + (size_t)18 * N);

    k_compute_W<<<1, 384, 0, stream>>>(basis1, comp1, basis2, comp2, B, W1, W2);

    int grdN = (N + 255) / 256;
    k_pack_x<<<grdN, 256, 0, stream>>>(x, xq, N);

    k_part_count<<<NT, TILE_T, 0, stream>>>(dst, cnt, E, NBUCK, NT);

    int NB = (SLEN + SCAN_TILE - 1) / SCAN_TILE;
    k_scan_block<<<NB, SCAN_BLOCK, 0, stream>>>(cnt, bsums, SLEN);
    k_scan_top<<<1, 1024, 0, stream>>>(bsums, NB);
    k_scan_add<<<(SLEN + 255) / 256, 256, 0, stream>>>(cnt, bsums, SLEN);

    k_part_scatter<<<NT, TILE_T, 0, stream>>>(src, dst, etype, cnt, part, E, NBUCK, NT);

    k_bucket_sort<<<NBUCK, BW, 0, stream>>>(cnt, part, csr, offg, E, NBUCK, NT, N);

    int NSEG = 3 * N;
    int grdS = (NSEG + 255) / 256;
    k_layer1a<<<grdS, 256, 0, stream>>>(offg, csr, xq, mxq, NSEG);
    k_layer1b<<<grdN, 256, 0, stream>>>(x, mxq, W1, root1, bias1, hq, hq8, N);

    k_layer2a<<<grdS, 256, 0, stream>>>(offg, csr, hq8, W2, partialq, N);

    k_layer2b<<<grdN, 256, 0, stream>>>(hq, (const uint4*)partialq, root2, bias2, out, N);
}

// Round 13
// 371.281 us; speedup vs baseline: 10.5844x; 1.0952x over previous
//
#include <hip/hip_runtime.h>

#define RELS 3
#define IN1  3
#define HID  16
#define OUT2 8

#define BW     256                 // dsts per bucket (== 1<<8)
#define BINS   1024                // (local_dst<<2)|type bins
#define MAXB   1024
#define TILE_T 256
#define TILE_I 16
#define TILE   (TILE_T * TILE_I)   // 4096 edges per partition block

#define SCAN_BLOCK 256
#define SCAN_ITEMS 8
#define SCAN_TILE  (SCAN_BLOCK * SCAN_ITEMS)   // 2048

#define CMAX 10240                 // LDS staging capacity in pass C (edges)

__device__ __forceinline__ float bf_lo(unsigned u) { return __uint_as_float(u << 16); }
__device__ __forceinline__ float bf_hi(unsigned u) { return __uint_as_float(u & 0xFFFF0000u); }
__device__ __forceinline__ unsigned pack_bf16(float a, float b) {
    unsigned ua = __float_as_uint(a);
    unsigned ub = __float_as_uint(b);
    ua = (ua + 0x7FFFu + ((ua >> 16) & 1u)) >> 16;
    ub = (ub + 0x7FFFu + ((ub >> 16) & 1u)) >> 16;
    return ua | (ub << 16);
}

// fp8 e4m3 (bias 7), nonnegative inputs only (post-ReLU), subnormal-preserving
__device__ __forceinline__ unsigned enc_fp8(float f) {
    if (f < 0.015625f) return (unsigned)(f * 512.0f + 0.5f);   // subnormal: u = round(f*2^9)
    unsigned bits = __float_as_uint(f);
    unsigned r = bits + 0x7FFFFu + ((bits >> 20) & 1u);        // RNE to 3 mantissa bits
    unsigned u = (r >> 20) - 960u;
    return u > 127u ? 127u : u;
}
__device__ __forceinline__ float dec_fp8(unsigned u) {
    return (u >= 8u) ? __uint_as_float((u + 960u) << 20) : (float)u * 0.001953125f;
}

// accumulate a 16-byte fp8 row into s[16]
__device__ __forceinline__ void acc_fp8row(uint4 q, float* s) {
    unsigned w;
#pragma unroll
    for (int j = 0; j < 4; ++j) {
        w = (j == 0) ? q.x : (j == 1) ? q.y : (j == 2) ? q.z : q.w;
#pragma unroll
        for (int b = 0; b < 4; ++b)
            s[j * 4 + b] += dec_fp8((w >> (8 * b)) & 0xFFu);
    }
}

// ---------------- W = comp @ basis (tiny) ----------------
__global__ void k_compute_W(const float* __restrict__ basis1, const float* __restrict__ comp1,
                            const float* __restrict__ basis2, const float* __restrict__ comp2,
                            int B, float* __restrict__ W1, float* __restrict__ W2) {
    int tid = threadIdx.x;
    if (tid < RELS * IN1 * HID) {
        int r = tid / (IN1 * HID), io = tid % (IN1 * HID);
        float acc = 0.f;
        for (int b = 0; b < B; ++b) acc += comp1[r * B + b] * basis1[b * IN1 * HID + io];
        W1[tid] = acc;
    }
    if (tid < RELS * HID * OUT2) {
        int r = tid / (HID * OUT2), io = tid % (HID * OUT2);
        float acc = 0.f;
        for (int b = 0; b < B; ++b) acc += comp2[r * B + b] * basis2[b * HID * OUT2 + io];
        W2[tid] = acc;
    }
}

// ---------------- pack x into bf16x3 (8B) ----------------
__global__ void k_pack_x(const float* __restrict__ x, uint2* __restrict__ xq, int N) {
    int n = blockIdx.x * blockDim.x + threadIdx.x;
    if (n >= N) return;
    float x0 = x[3 * n + 0], x1 = x[3 * n + 1], x2 = x[3 * n + 2];
    xq[n] = make_uint2(pack_bf16(x0, x1), pack_bf16(x2, 0.f));
}

// ---------------- pass A: per-block bucket histogram (LDS atomics only) ----------------
__global__ void k_part_count(const int* __restrict__ dst, int* __restrict__ cnt,
                             int E, int NBUCK, int NT) {
    __shared__ int hist[MAXB];
    for (int i = threadIdx.x; i < NBUCK; i += TILE_T) hist[i] = 0;
    __syncthreads();
    int base = blockIdx.x * TILE;
#pragma unroll 4
    for (int k = 0; k < TILE_I; ++k) {
        int e = base + k * TILE_T + threadIdx.x;
        if (e < E) atomicAdd(&hist[dst[e] >> 8], 1);
    }
    __syncthreads();
    for (int b = threadIdx.x; b < NBUCK; b += TILE_T)
        cnt[(size_t)b * NT + blockIdx.x] = hist[b];
}

// ---------------- scans ----------------
__global__ void k_scan_block(int* __restrict__ data, int* __restrict__ bsums, int S) {
    __shared__ int lds[SCAN_BLOCK];
    int base = blockIdx.x * SCAN_TILE + threadIdx.x * SCAN_ITEMS;
    int v[SCAN_ITEMS];
    int tot = 0;
#pragma unroll
    for (int k = 0; k < SCAN_ITEMS; ++k) {
        int i = base + k;
        v[k] = (i < S) ? data[i] : 0;
        tot += v[k];
    }
    lds[threadIdx.x] = tot;
    __syncthreads();
    for (int d = 1; d < SCAN_BLOCK; d <<= 1) {
        int val = lds[threadIdx.x];
        int add = (threadIdx.x >= d) ? lds[threadIdx.x - d] : 0;
        __syncthreads();
        lds[threadIdx.x] = val + add;
        __syncthreads();
    }
    int excl = (threadIdx.x == 0) ? 0 : lds[threadIdx.x - 1];
    if (threadIdx.x == SCAN_BLOCK - 1) bsums[blockIdx.x] = lds[SCAN_BLOCK - 1];
    int run = excl;
#pragma unroll
    for (int k = 0; k < SCAN_ITEMS; ++k) {
        int i = base + k;
        if (i < S) data[i] = run;
        run += v[k];
    }
}

__global__ void k_scan_top(int* __restrict__ bsums, int NB) {
    __shared__ int lds[1024];
    int t = threadIdx.x;
    lds[t] = (t < NB) ? bsums[t] : 0;
    __syncthreads();
    for (int d = 1; d < 1024; d <<= 1) {
        int val = lds[t];
        int add = (t >= d) ? lds[t - d] : 0;
        __syncthreads();
        lds[t] = val + add;
        __syncthreads();
    }
    int excl = (t == 0) ? 0 : lds[t - 1];
    if (t < NB) bsums[t] = excl;
}

__global__ void k_scan_add(int* __restrict__ data, const int* __restrict__ bsums, int S) {
    int i = blockIdx.x * blockDim.x + threadIdx.x;
    if (i < S) data[i] += bsums[i / SCAN_TILE];
}

// ---------------- pass B: block-local counting sort by bucket, coalesced flush ----------
// Register-staged: src/dst/et read ONCE; pass 2 is pure LDS.
__global__ void k_part_scatter(const int* __restrict__ src, const int* __restrict__ dst,
                               const int* __restrict__ et, const int* __restrict__ off_e,
                               unsigned* __restrict__ part, int E, int NBUCK, int NT) {
    __shared__ int cnt[MAXB];             // counts, then reused as local cursor
    __shared__ int bscan[TILE_T];
    __shared__ int base_l[MAXB];
    __shared__ int gbase[MAXB];
    __shared__ unsigned loc[TILE];
    __shared__ unsigned short bid[TILE];
    int t = threadIdx.x;
    int blk = blockIdx.x;
    for (int i = t; i < NBUCK; i += TILE_T) cnt[i] = 0;
    __syncthreads();
    int base = blk * TILE;
    int sz = min(TILE, E - base);
    // pass 1: load once, pack into registers, count buckets
    unsigned pkreg[TILE_I];
    int breg[TILE_I];
#pragma unroll
    for (int k = 0; k < TILE_I; ++k) {
        int e = base + k * TILE_T + t;
        breg[k] = -1;
        if (e < E) {
            int d = dst[e];
            int b = d >> 8;
            breg[k] = b;
            pkreg[k] = ((unsigned)(d & 255) << 20) | ((unsigned)et[e] << 18) | (unsigned)src[e];
            atomicAdd(&cnt[b], 1);
        }
    }
    __syncthreads();
    // exclusive scan over NBUCK bins (4 bins/thread)
    int c[4];
    int tot = 0;
#pragma unroll
    for (int j = 0; j < 4; ++j) {
        int b = t * 4 + j;
        c[j] = (b < NBUCK) ? cnt[b] : 0;
        tot += c[j];
    }
    bscan[t] = tot;
    __syncthreads();
    for (int d = 1; d < TILE_T; d <<= 1) {
        int val = bscan[t];
        int add = (t >= d) ? bscan[t - d] : 0;
        __syncthreads();
        bscan[t] = val + add;
        __syncthreads();
    }
    int run = (t == 0) ? 0 : bscan[t - 1];
#pragma unroll
    for (int j = 0; j < 4; ++j) {
        int b = t * 4 + j;
        if (b < NBUCK) { base_l[b] = run; cnt[b] = run; }  // cnt becomes cursor
        run += c[j];
    }
    for (int i = t; i < NBUCK; i += TILE_T)
        gbase[i] = off_e[(size_t)i * NT + blk];
    __syncthreads();
    // pass 2: place packed edges into LDS, bucket-grouped (pure LDS)
#pragma unroll
    for (int k = 0; k < TILE_I; ++k) {
        if (breg[k] >= 0) {
            int slot = atomicAdd(&cnt[breg[k]], 1);
            loc[slot] = pkreg[k];
            bid[slot] = (unsigned short)breg[k];
        }
    }
    __syncthreads();
    // flush: consecutive threads -> consecutive global addresses within each run
    for (int i = t; i < sz; i += TILE_T) {
        int b = bid[i];
        part[gbase[b] + (i - base_l[b])] = loc[i];
    }
}

// ---------------- pass C: per-bucket counting sort by (ldst,type) -> CSR + seg offsets ---
__global__ void k_bucket_sort(const int* __restrict__ off_e, const unsigned* __restrict__ part,
                              unsigned* __restrict__ csr, int* __restrict__ off_g,
                              int E, int NBUCK, int NT, int N) {
    __shared__ int cnt[BINS];
    __shared__ int tsum[BW];
    __shared__ int cur[BINS];
    __shared__ unsigned loc[CMAX];
    int b = blockIdx.x, t = threadIdx.x;
    int bs = off_e[(size_t)b * NT];
    int be = (b + 1 < NBUCK) ? off_e[(size_t)(b + 1) * NT] : E;
    int sz = be - bs;
#pragma unroll
    for (int j = 0; j < 4; ++j) cnt[t * 4 + j] = 0;
    __syncthreads();
    for (int i = t; i < sz; i += BW)
        atomicAdd(&cnt[part[bs + i] >> 18], 1);
    __syncthreads();
    int c0 = cnt[4 * t + 0], c1 = cnt[4 * t + 1], c2 = cnt[4 * t + 2], c3 = cnt[4 * t + 3];
    int p1 = c0, p2 = c0 + c1, p3 = c0 + c1 + c2;
    tsum[t] = p3 + c3;
    __syncthreads();
    for (int d = 1; d < BW; d <<= 1) {
        int val = tsum[t];
        int add = (t >= d) ? tsum[t - d] : 0;
        __syncthreads();
        tsum[t] = val + add;
        __syncthreads();
    }
    int excl = (t == 0) ? 0 : tsum[t - 1];
    cur[4 * t + 0] = excl;
    cur[4 * t + 1] = excl + p1;
    cur[4 * t + 2] = excl + p2;
    cur[4 * t + 3] = excl + p3;
    int n = b * BW + t;
    if (n < N) {
        off_g[(size_t)n * 3 + 0] = bs + excl;
        off_g[(size_t)n * 3 + 1] = bs + excl + p1;
        off_g[(size_t)n * 3 + 2] = bs + excl + p2;
    } else if (n == N) {
        off_g[(size_t)N * 3] = bs + excl;
    }
    if (b == NBUCK - 1 && t == BW - 1) off_g[(size_t)N * 3] = E;
    __syncthreads();
    if (sz <= CMAX) {
        for (int i = t; i < sz; i += BW) {
            unsigned v = part[bs + i];
            int p = atomicAdd(&cur[v >> 18], 1);
            loc[p] = v & 0x3FFFF;
        }
        __syncthreads();
        for (int i = t; i < sz; i += BW) csr[bs + i] = loc[i];
    } else {
        for (int i = t; i < sz; i += BW) {
            unsigned v = part[bs + i];
            int p = atomicAdd(&cur[v >> 18], 1);
            csr[bs + p] = v & 0x3FFFF;
        }
    }
}

// ---------------- layer1a: per (r,n) segment: mean(xq[src]) -> mxq (bf16x3) ----------
__global__ void k_layer1a(const int* __restrict__ off_g, const unsigned* __restrict__ csr,
                          const uint2* __restrict__ xq, unsigned* __restrict__ mxq, int NSEG) {
    int seg = blockIdx.x * blockDim.x + threadIdx.x;
    if (seg >= NSEG) return;
    int a = off_g[seg], b = off_g[seg + 1];
    float s0 = 0.f, s1 = 0.f, s2 = 0.f;
    int e = a;
    for (; e + 4 <= b; e += 4) {
        unsigned i0 = __builtin_nontemporal_load(csr + e);
        unsigned i1 = __builtin_nontemporal_load(csr + e + 1);
        unsigned i2 = __builtin_nontemporal_load(csr + e + 2);
        unsigned i3 = __builtin_nontemporal_load(csr + e + 3);
        uint2 v0 = xq[i0], v1 = xq[i1], v2 = xq[i2], v3 = xq[i3];
        s0 += bf_lo(v0.x) + bf_lo(v1.x) + bf_lo(v2.x) + bf_lo(v3.x);
        s1 += bf_hi(v0.x) + bf_hi(v1.x) + bf_hi(v2.x) + bf_hi(v3.x);
        s2 += bf_lo(v0.y) + bf_lo(v1.y) + bf_lo(v2.y) + bf_lo(v3.y);
    }
    for (; e < b; ++e) {
        uint2 v = xq[__builtin_nontemporal_load(csr + e)];
        s0 += bf_lo(v.x);
        s1 += bf_hi(v.x);
        s2 += bf_lo(v.y);
    }
    float inv = 1.0f / fmaxf((float)(b - a), 1.0f);
    unsigned* p = mxq + (size_t)seg * 2;
    __builtin_nontemporal_store(pack_bf16(s0 * inv, s1 * inv), p);
    __builtin_nontemporal_store(pack_bf16(s2 * inv, 0.f), p + 1);
}

// ---------------- layer1b: means @ W1 + x@root1 + bias -> relu -> hq (bf16) + hq8 (fp8) --
__global__ void k_layer1b(const float* __restrict__ x, const unsigned* __restrict__ mxq,
                          const float* __restrict__ W1, const float* __restrict__ root1,
                          const float* __restrict__ bias1,
                          unsigned* __restrict__ hq, uint4* __restrict__ hq8, int N) {
    __shared__ float sW1[RELS * IN1 * HID];
    __shared__ float sR1[IN1 * HID];
    __shared__ float sB1[HID];
    for (int i = threadIdx.x; i < RELS * IN1 * HID; i += blockDim.x) sW1[i] = W1[i];
    for (int i = threadIdx.x; i < IN1 * HID; i += blockDim.x) sR1[i] = root1[i];
    for (int i = threadIdx.x; i < HID; i += blockDim.x) sB1[i] = bias1[i];
    __syncthreads();
    int n = blockIdx.x * blockDim.x + threadIdx.x;
    if (n >= N) return;

    float acc[HID];
    float xv0 = x[3 * n + 0], xv1 = x[3 * n + 1], xv2 = x[3 * n + 2];
#pragma unroll
    for (int o = 0; o < HID; ++o)
        acc[o] = sB1[o] + xv0 * sR1[0 * HID + o] + xv1 * sR1[1 * HID + o] + xv2 * sR1[2 * HID + o];

#pragma unroll
    for (int r = 0; r < RELS; ++r) {
        unsigned m0w = mxq[((size_t)n * 3 + r) * 2];
        unsigned m1w = mxq[((size_t)n * 3 + r) * 2 + 1];
        float m0 = bf_lo(m0w), m1 = bf_hi(m0w), m2 = bf_lo(m1w);
        const float* w = sW1 + r * IN1 * HID;
#pragma unroll
        for (int o = 0; o < HID; ++o)
            acc[o] += m0 * w[0 * HID + o] + m1 * w[1 * HID + o] + m2 * w[2 * HID + o];
    }

    float hv[HID];
#pragma unroll
    for (int o = 0; o < HID; ++o) hv[o] = fmaxf(acc[o], 0.f);

    unsigned q[8];
#pragma unroll
    for (int j = 0; j < 8; ++j) q[j] = pack_bf16(hv[2 * j], hv[2 * j + 1]);
    uint4* hp = reinterpret_cast<uint4*>(hq + (size_t)n * 8);
    hp[0] = make_uint4(q[0], q[1], q[2], q[3]);
    hp[1] = make_uint4(q[4], q[5], q[6], q[7]);

    unsigned f8[4];
#pragma unroll
    for (int j = 0; j < 4; ++j) {
        f8[j] = enc_fp8(hv[4 * j + 0])
              | (enc_fp8(hv[4 * j + 1]) << 8)
              | (enc_fp8(hv[4 * j + 2]) << 16)
              | (enc_fp8(hv[4 * j + 3]) << 24);
    }
    hq8[n] = make_uint4(f8[0], f8[1], f8[2], f8[3]);
}

// ---------------- layer2a: per (r,n) segment: mean(h8[src]) @ W2[r] -> partialq (bf16) --
__global__ void k_layer2a(const int* __restrict__ off_g, const unsigned* __restrict__ csr,
                          const uint4* __restrict__ hq8, const float* __restrict__ W2,
                          unsigned* __restrict__ partialq, int N) {
    __shared__ float sW2[RELS * HID * OUT2];
    for (int i = threadIdx.x; i < RELS * HID * OUT2; i += blockDim.x) sW2[i] = W2[i];
    __syncthreads();
    int seg = blockIdx.x * blockDim.x + threadIdx.x;
    if (seg >= 3 * N) return;
    int r = seg % 3;
    int a = off_g[seg], bnd = off_g[seg + 1];

    float s[HID];
#pragma unroll
    for (int i = 0; i < HID; ++i) s[i] = 0.f;
    int e = a;
    for (; e + 4 <= bnd; e += 4) {
        unsigned i0 = __builtin_nontemporal_load(csr + e);
        unsigned i1 = __builtin_nontemporal_load(csr + e + 1);
        unsigned i2 = __builtin_nontemporal_load(csr + e + 2);
        unsigned i3 = __builtin_nontemporal_load(csr + e + 3);
        uint4 q0 = hq8[i0], q1 = hq8[i1], q2 = hq8[i2], q3 = hq8[i3];
        acc_fp8row(q0, s);
        acc_fp8row(q1, s);
        acc_fp8row(q2, s);
        acc_fp8row(q3, s);
    }
    for (; e < bnd; ++e) {
        uint4 q = hq8[__builtin_nontemporal_load(csr + e)];
        acc_fp8row(q, s);
    }
    float inv = 1.0f / fmaxf((float)(bnd - a), 1.0f);
    float o8[OUT2];
#pragma unroll
    for (int o = 0; o < OUT2; ++o) o8[o] = 0.f;
    const float* w = sW2 + r * HID * OUT2;
#pragma unroll
    for (int i = 0; i < HID; ++i) {
        float sv = s[i] * inv;
#pragma unroll
        for (int o = 0; o < OUT2; ++o) o8[o] += sv * w[i * OUT2 + o];
    }
    unsigned* p = partialq + (size_t)seg * 4;
    __builtin_nontemporal_store(pack_bf16(o8[0], o8[1]), p);
    __builtin_nontemporal_store(pack_bf16(o8[2], o8[3]), p + 1);
    __builtin_nontemporal_store(pack_bf16(o8[4], o8[5]), p + 2);
    __builtin_nontemporal_store(pack_bf16(o8[6], o8[7]), p + 3);
}

// ---------------- layer2b: partials + h@root2 + bias2 -> log_softmax ----------------
__global__ void k_layer2b(const unsigned* __restrict__ hq, const uint4* __restrict__ partialq,
                          const float* __restrict__ root2, const float* __restrict__ bias2,
                          float* __restrict__ out, int N) {
    __shared__ float sR2[HID * OUT2];
    __shared__ float sB2[OUT2];
    for (int i = threadIdx.x; i < HID * OUT2; i += blockDim.x) sR2[i] = root2[i];
    for (int i = threadIdx.x; i < OUT2; i += blockDim.x) sB2[i] = bias2[i];
    __syncthreads();
    int n = blockIdx.x * blockDim.x + threadIdx.x;
    if (n >= N) return;

    float acc[OUT2];
#pragma unroll
    for (int o = 0; o < OUT2; ++o) acc[o] = sB2[o];
#pragma unroll
    for (int r = 0; r < RELS; ++r) {
        uint4 P = partialq[(size_t)n * 3 + r];
        acc[0] += bf_lo(P.x); acc[1] += bf_hi(P.x);
        acc[2] += bf_lo(P.y); acc[3] += bf_hi(P.y);
        acc[4] += bf_lo(P.z); acc[5] += bf_hi(P.z);
        acc[6] += bf_lo(P.w); acc[7] += bf_hi(P.w);
    }

    const uint4* hp = reinterpret_cast<const uint4*>(hq + (size_t)n * 8);
    uint4 q0 = hp[0], q1 = hp[1];
    float hv[HID] = {
        bf_lo(q0.x), bf_hi(q0.x), bf_lo(q0.y), bf_hi(q0.y),
        bf_lo(q0.z), bf_hi(q0.z), bf_lo(q0.w), bf_hi(q0.w),
        bf_lo(q1.x), bf_hi(q1.x), bf_lo(q1.y), bf_hi(q1.y),
        bf_lo(q1.z), bf_hi(q1.z), bf_lo(q1.w), bf_hi(q1.w)
    };
#pragma unroll
    for (int i = 0; i < HID; ++i)
#pragma unroll
        for (int o = 0; o < OUT2; ++o) acc[o] += hv[i] * sR2[i * OUT2 + o];

    float mx = acc[0];
#pragma unroll
    for (int o = 1; o < OUT2; ++o) mx = fmaxf(mx, acc[o]);
    float ssum = 0.f;
#pragma unroll
    for (int o = 0; o < OUT2; ++o) ssum += expf(acc[o] - mx);
    float lse = logf(ssum) + mx;
    float* op = out + (size_t)n * OUT2;
    float4 lo = {acc[0] - lse, acc[1] - lse, acc[2] - lse, acc[3] - lse};
    float4 hi = {acc[4] - lse, acc[5] - lse, acc[6] - lse, acc[7] - lse};
    *reinterpret_cast<float4*>(op) = lo;
    *reinterpret_cast<float4*>(op + 4) = hi;
}

extern "C" void kernel_launch(void* const* d_in, const int* in_sizes, int n_in,
                              void* d_out, int out_size, void* d_ws, size_t ws_size,
                              hipStream_t stream) {
    const float* x      = (const float*)d_in[0];
    const int*   eidx   = (const int*)d_in[1];
    const int*   etype  = (const int*)d_in[2];
    const float* basis1 = (const float*)d_in[3];
    const float* comp1  = (const float*)d_in[4];
    const float* root1  = (const float*)d_in[5];
    const float* bias1  = (const float*)d_in[6];
    const float* basis2 = (const float*)d_in[7];
    const float* comp2  = (const float*)d_in[8];
    const float* root2  = (const float*)d_in[9];
    const float* bias2  = (const float*)d_in[10];
    float* out = (float*)d_out;

    const int N = in_sizes[0] / IN1;
    const int E = in_sizes[2];
    const int B = in_sizes[3] / (IN1 * HID);

    const int* src = eidx;
    const int* dst = eidx + E;

    const int NBUCK = (N + BW - 1) / BW;        // 782
    const int NT    = (E + TILE - 1) / TILE;    // 1563
    const int SLEN  = NBUCK * NT;

    char* wsb = (char*)d_ws;
    size_t off_w = 0;
    auto alloc_w = [&](size_t words) {
        void* p = wsb + off_w * 4;
        off_w += (words + 15) & ~(size_t)15;
        return p;
    };
    int*      cnt   = (int*)alloc_w(SLEN);          // scanned in place -> off_e
    int*      bsums = (int*)alloc_w(1024);
    unsigned* part  = (unsigned*)alloc_w(E);        // reused after pass C (see below)
    unsigned* csr   = (unsigned*)alloc_w(E);
    int*      offg  = (int*)alloc_w((size_t)N * 3 + 16);
    float*    W1    = (float*)alloc_w(RELS * IN1 * HID);
    float*    W2    = (float*)alloc_w(RELS * HID * OUT2);
    unsigned* hq    = (unsigned*)alloc_w((size_t)N * 8);   // h in bf16, 32B per node
    uint2*    xq    = (uint2*)alloc_w((size_t)N * 2);      // x in bf16x3, 8B per node
    // aliases inside dead part[] (raw edges consumed by bucket_sort):
    //   partialq: 3N uint4 (bf16 partials)  @ part + 0       (12N words)
    //   mxq:      3N uint2 (bf16 means)     @ part + 12N     (6N words)
    //   hq8:      N  uint4 (fp8 h rows)     @ part + 18N     (4N words)   [22N <= E]
    unsigned* partialq = part;
    unsigned* mxq      = part + (size_t)12 * N;
    uint4*    hq8      = (uint4*)(part + (size_t)18 * N);

    k_compute_W<<<1, 384, 0, stream>>>(basis1, comp1, basis2, comp2, B, W1, W2);

    int grdN = (N + 255) / 256;
    k_pack_x<<<grdN, 256, 0, stream>>>(x, xq, N);

    k_part_count<<<NT, TILE_T, 0, stream>>>(dst, cnt, E, NBUCK, NT);

    int NB = (SLEN + SCAN_TILE - 1) / SCAN_TILE;
    k_scan_block<<<NB, SCAN_BLOCK, 0, stream>>>(cnt, bsums, SLEN);
    k_scan_top<<<1, 1024, 0, stream>>>(bsums, NB);
    k_scan_add<<<(SLEN + 255) / 256, 256, 0, stream>>>(cnt, bsums, SLEN);

    k_part_scatter<<<NT, TILE_T, 0, stream>>>(src, dst, etype, cnt, part, E, NBUCK, NT);

    k_bucket_sort<<<NBUCK, BW, 0, stream>>>(cnt, part, csr, offg, E, NBUCK, NT, N);

    int NSEG = 3 * N;
    int grdS = (NSEG + 255) / 256;
    k_layer1a<<<grdS, 256, 0, stream>>>(offg, csr, xq, mxq, NSEG);
    k_layer1b<<<grdN, 256, 0, stream>>>(x, mxq, W1, root1, bias1, hq, hq8, N);

    k_layer2a<<<grdS, 256, 0, stream>>>(offg, csr, hq8, W2, partialq, N);

    k_layer2b<<<grdN, 256, 0, stream>>>(hq, (const uint4*)partialq, root2, bias2, out, N);
}

// Round 14
// 360.341 us; speedup vs baseline: 10.9057x; 1.0304x over previous
//
#include <hip/hip_runtime.h>

#define RELS 3
#define IN1  3
#define HID  16
#define OUT2 8

#define BW     256                 // dsts per bucket (== 1<<8)
#define BINS   1024                // (local_dst<<2)|type bins
#define MAXB   1024
#define TILE_T 256
#define TILE_I 16
#define TILE   (TILE_T * TILE_I)   // 4096 edges per partition block

#define SCAN_BLOCK 256
#define SCAN_ITEMS 8
#define SCAN_TILE  (SCAN_BLOCK * SCAN_ITEMS)   // 2048

#define CMAX 10240                 // LDS staging capacity in pass C (edges)

typedef float floatx2 __attribute__((ext_vector_type(2)));

__device__ __forceinline__ float bf_lo(unsigned u) { return __uint_as_float(u << 16); }
__device__ __forceinline__ float bf_hi(unsigned u) { return __uint_as_float(u & 0xFFFF0000u); }
__device__ __forceinline__ unsigned pack_bf16(float a, float b) {
    unsigned ua = __float_as_uint(a);
    unsigned ub = __float_as_uint(b);
    ua = (ua + 0x7FFFu + ((ua >> 16) & 1u)) >> 16;
    ub = (ub + 0x7FFFu + ((ub >> 16) & 1u)) >> 16;
    return ua | (ub << 16);
}

// accumulate a 16-byte fp8 row into s[16] using HW fp8->f32 converters
__device__ __forceinline__ void acc_fp8row(uint4 q, float* s) {
#pragma unroll
    for (int j = 0; j < 4; ++j) {
        unsigned w = (j == 0) ? q.x : (j == 1) ? q.y : (j == 2) ? q.z : q.w;
        floatx2 lo = __builtin_amdgcn_cvt_pk_f32_fp8((int)w, false);
        floatx2 hi = __builtin_amdgcn_cvt_pk_f32_fp8((int)w, true);
        s[j * 4 + 0] += lo.x;
        s[j * 4 + 1] += lo.y;
        s[j * 4 + 2] += hi.x;
        s[j * 4 + 3] += hi.y;
    }
}

// ---------------- W = comp @ basis (tiny) ----------------
__global__ void k_compute_W(const float* __restrict__ basis1, const float* __restrict__ comp1,
                            const float* __restrict__ basis2, const float* __restrict__ comp2,
                            int B, float* __restrict__ W1, float* __restrict__ W2) {
    int tid = threadIdx.x;
    if (tid < RELS * IN1 * HID) {
        int r = tid / (IN1 * HID), io = tid % (IN1 * HID);
        float acc = 0.f;
        for (int b = 0; b < B; ++b) acc += comp1[r * B + b] * basis1[b * IN1 * HID + io];
        W1[tid] = acc;
    }
    if (tid < RELS * HID * OUT2) {
        int r = tid / (HID * OUT2), io = tid % (HID * OUT2);
        float acc = 0.f;
        for (int b = 0; b < B; ++b) acc += comp2[r * B + b] * basis2[b * HID * OUT2 + io];
        W2[tid] = acc;
    }
}

// ---------------- pack x into bf16x3 (8B) ----------------
__global__ void k_pack_x(const float* __restrict__ x, uint2* __restrict__ xq, int N) {
    int n = blockIdx.x * blockDim.x + threadIdx.x;
    if (n >= N) return;
    float x0 = x[3 * n + 0], x1 = x[3 * n + 1], x2 = x[3 * n + 2];
    xq[n] = make_uint2(pack_bf16(x0, x1), pack_bf16(x2, 0.f));
}

// ---------------- pass A: per-block bucket histogram (LDS atomics only) ----------------
__global__ void k_part_count(const int* __restrict__ dst, int* __restrict__ cnt,
                             int E, int NBUCK, int NT) {
    __shared__ int hist[MAXB];
    for (int i = threadIdx.x; i < NBUCK; i += TILE_T) hist[i] = 0;
    __syncthreads();
    int base = blockIdx.x * TILE;
#pragma unroll 4
    for (int k = 0; k < TILE_I; ++k) {
        int e = base + k * TILE_T + threadIdx.x;
        if (e < E) atomicAdd(&hist[dst[e] >> 8], 1);
    }
    __syncthreads();
    for (int b = threadIdx.x; b < NBUCK; b += TILE_T)
        cnt[(size_t)b * NT + blockIdx.x] = hist[b];
}

// ---------------- scans ----------------
__global__ void k_scan_block(int* __restrict__ data, int* __restrict__ bsums, int S) {
    __shared__ int lds[SCAN_BLOCK];
    int base = blockIdx.x * SCAN_TILE + threadIdx.x * SCAN_ITEMS;
    int v[SCAN_ITEMS];
    int tot = 0;
#pragma unroll
    for (int k = 0; k < SCAN_ITEMS; ++k) {
        int i = base + k;
        v[k] = (i < S) ? data[i] : 0;
        tot += v[k];
    }
    lds[threadIdx.x] = tot;
    __syncthreads();
    for (int d = 1; d < SCAN_BLOCK; d <<= 1) {
        int val = lds[threadIdx.x];
        int add = (threadIdx.x >= d) ? lds[threadIdx.x - d] : 0;
        __syncthreads();
        lds[threadIdx.x] = val + add;
        __syncthreads();
    }
    int excl = (threadIdx.x == 0) ? 0 : lds[threadIdx.x - 1];
    if (threadIdx.x == SCAN_BLOCK - 1) bsums[blockIdx.x] = lds[SCAN_BLOCK - 1];
    int run = excl;
#pragma unroll
    for (int k = 0; k < SCAN_ITEMS; ++k) {
        int i = base + k;
        if (i < S) data[i] = run;
        run += v[k];
    }
}

__global__ void k_scan_top(int* __restrict__ bsums, int NB) {
    __shared__ int lds[1024];
    int t = threadIdx.x;
    lds[t] = (t < NB) ? bsums[t] : 0;
    __syncthreads();
    for (int d = 1; d < 1024; d <<= 1) {
        int val = lds[t];
        int add = (t >= d) ? lds[t - d] : 0;
        __syncthreads();
        lds[t] = val + add;
        __syncthreads();
    }
    int excl = (t == 0) ? 0 : lds[t - 1];
    if (t < NB) bsums[t] = excl;
}

__global__ void k_scan_add(int* __restrict__ data, const int* __restrict__ bsums, int S) {
    int i = blockIdx.x * blockDim.x + threadIdx.x;
    if (i < S) data[i] += bsums[i / SCAN_TILE];
}

// ---------------- pass B: block-local counting sort by bucket, coalesced flush ----------
// Register-staged: src/dst/et read ONCE; pass 2 is pure LDS.
__global__ void k_part_scatter(const int* __restrict__ src, const int* __restrict__ dst,
                               const int* __restrict__ et, const int* __restrict__ off_e,
                               unsigned* __restrict__ part, int E, int NBUCK, int NT) {
    __shared__ int cnt[MAXB];             // counts, then reused as local cursor
    __shared__ int bscan[TILE_T];
    __shared__ int base_l[MAXB];
    __shared__ int gbase[MAXB];
    __shared__ unsigned loc[TILE];
    __shared__ unsigned short bid[TILE];
    int t = threadIdx.x;
    int blk = blockIdx.x;
    for (int i = t; i < NBUCK; i += TILE_T) cnt[i] = 0;
    __syncthreads();
    int base = blk * TILE;
    int sz = min(TILE, E - base);
    // pass 1: load once, pack into registers, count buckets
    unsigned pkreg[TILE_I];
    int breg[TILE_I];
#pragma unroll
    for (int k = 0; k < TILE_I; ++k) {
        int e = base + k * TILE_T + t;
        breg[k] = -1;
        if (e < E) {
            int d = dst[e];
            int b = d >> 8;
            breg[k] = b;
            pkreg[k] = ((unsigned)(d & 255) << 20) | ((unsigned)et[e] << 18) | (unsigned)src[e];
            atomicAdd(&cnt[b], 1);
        }
    }
    __syncthreads();
    // exclusive scan over NBUCK bins (4 bins/thread)
    int c[4];
    int tot = 0;
#pragma unroll
    for (int j = 0; j < 4; ++j) {
        int b = t * 4 + j;
        c[j] = (b < NBUCK) ? cnt[b] : 0;
        tot += c[j];
    }
    bscan[t] = tot;
    __syncthreads();
    for (int d = 1; d < TILE_T; d <<= 1) {
        int val = bscan[t];
        int add = (t >= d) ? bscan[t - d] : 0;
        __syncthreads();
        bscan[t] = val + add;
        __syncthreads();
    }
    int run = (t == 0) ? 0 : bscan[t - 1];
#pragma unroll
    for (int j = 0; j < 4; ++j) {
        int b = t * 4 + j;
        if (b < NBUCK) { base_l[b] = run; cnt[b] = run; }  // cnt becomes cursor
        run += c[j];
    }
    for (int i = t; i < NBUCK; i += TILE_T)
        gbase[i] = off_e[(size_t)i * NT + blk];
    __syncthreads();
    // pass 2: place packed edges into LDS, bucket-grouped (pure LDS)
#pragma unroll
    for (int k = 0; k < TILE_I; ++k) {
        if (breg[k] >= 0) {
            int slot = atomicAdd(&cnt[breg[k]], 1);
            loc[slot] = pkreg[k];
            bid[slot] = (unsigned short)breg[k];
        }
    }
    __syncthreads();
    // flush: consecutive threads -> consecutive global addresses within each run
    for (int i = t; i < sz; i += TILE_T) {
        int b = bid[i];
        part[gbase[b] + (i - base_l[b])] = loc[i];
    }
}

// ---------------- pass C: per-bucket counting sort by (ldst,type) -> CSR + seg offsets ---
__global__ void k_bucket_sort(const int* __restrict__ off_e, const unsigned* __restrict__ part,
                              unsigned* __restrict__ csr, int* __restrict__ off_g,
                              int E, int NBUCK, int NT, int N) {
    __shared__ int cnt[BINS];
    __shared__ int tsum[BW];
    __shared__ int cur[BINS];
    __shared__ unsigned loc[CMAX];
    int b = blockIdx.x, t = threadIdx.x;
    int bs = off_e[(size_t)b * NT];
    int be = (b + 1 < NBUCK) ? off_e[(size_t)(b + 1) * NT] : E;
    int sz = be - bs;
#pragma unroll
    for (int j = 0; j < 4; ++j) cnt[t * 4 + j] = 0;
    __syncthreads();
    for (int i = t; i < sz; i += BW)
        atomicAdd(&cnt[part[bs + i] >> 18], 1);
    __syncthreads();
    int c0 = cnt[4 * t + 0], c1 = cnt[4 * t + 1], c2 = cnt[4 * t + 2], c3 = cnt[4 * t + 3];
    int p1 = c0, p2 = c0 + c1, p3 = c0 + c1 + c2;
    tsum[t] = p3 + c3;
    __syncthreads();
    for (int d = 1; d < BW; d <<= 1) {
        int val = tsum[t];
        int add = (t >= d) ? tsum[t - d] : 0;
        __syncthreads();
        tsum[t] = val + add;
        __syncthreads();
    }
    int excl = (t == 0) ? 0 : tsum[t - 1];
    cur[4 * t + 0] = excl;
    cur[4 * t + 1] = excl + p1;
    cur[4 * t + 2] = excl + p2;
    cur[4 * t + 3] = excl + p3;
    int n = b * BW + t;
    if (n < N) {
        off_g[(size_t)n * 3 + 0] = bs + excl;
        off_g[(size_t)n * 3 + 1] = bs + excl + p1;
        off_g[(size_t)n * 3 + 2] = bs + excl + p2;
    } else if (n == N) {
        off_g[(size_t)N * 3] = bs + excl;
    }
    if (b == NBUCK - 1 && t == BW - 1) off_g[(size_t)N * 3] = E;
    __syncthreads();
    if (sz <= CMAX) {
        for (int i = t; i < sz; i += BW) {
            unsigned v = part[bs + i];
            int p = atomicAdd(&cur[v >> 18], 1);
            loc[p] = v & 0x3FFFF;
        }
        __syncthreads();
        for (int i = t; i < sz; i += BW) csr[bs + i] = loc[i];
    } else {
        for (int i = t; i < sz; i += BW) {
            unsigned v = part[bs + i];
            int p = atomicAdd(&cur[v >> 18], 1);
            csr[bs + p] = v & 0x3FFFF;
        }
    }
}

// ---------------- layer1a: per (r,n) segment: mean(xq[src]) -> mxq (bf16x3) ----------
__global__ void k_layer1a(const int* __restrict__ off_g, const unsigned* __restrict__ csr,
                          const uint2* __restrict__ xq, unsigned* __restrict__ mxq, int NSEG) {
    int seg = blockIdx.x * blockDim.x + threadIdx.x;
    if (seg >= NSEG) return;
    int a = off_g[seg], b = off_g[seg + 1];
    float s0 = 0.f, s1 = 0.f, s2 = 0.f;
    int e = a;
    for (; e + 4 <= b; e += 4) {
        unsigned i0 = __builtin_nontemporal_load(csr + e);
        unsigned i1 = __builtin_nontemporal_load(csr + e + 1);
        unsigned i2 = __builtin_nontemporal_load(csr + e + 2);
        unsigned i3 = __builtin_nontemporal_load(csr + e + 3);
        uint2 v0 = xq[i0], v1 = xq[i1], v2 = xq[i2], v3 = xq[i3];
        s0 += bf_lo(v0.x) + bf_lo(v1.x) + bf_lo(v2.x) + bf_lo(v3.x);
        s1 += bf_hi(v0.x) + bf_hi(v1.x) + bf_hi(v2.x) + bf_hi(v3.x);
        s2 += bf_lo(v0.y) + bf_lo(v1.y) + bf_lo(v2.y) + bf_lo(v3.y);
    }
    for (; e < b; ++e) {
        uint2 v = xq[__builtin_nontemporal_load(csr + e)];
        s0 += bf_lo(v.x);
        s1 += bf_hi(v.x);
        s2 += bf_lo(v.y);
    }
    float inv = 1.0f / fmaxf((float)(b - a), 1.0f);
    unsigned* p = mxq + (size_t)seg * 2;
    __builtin_nontemporal_store(pack_bf16(s0 * inv, s1 * inv), p);
    __builtin_nontemporal_store(pack_bf16(s2 * inv, 0.f), p + 1);
}

// ---------------- layer1b: means @ W1 + x@root1 + bias -> relu -> hq (bf16) + hq8 (fp8) --
__global__ void k_layer1b(const float* __restrict__ x, const unsigned* __restrict__ mxq,
                          const float* __restrict__ W1, const float* __restrict__ root1,
                          const float* __restrict__ bias1,
                          unsigned* __restrict__ hq, uint4* __restrict__ hq8, int N) {
    __shared__ float sW1[RELS * IN1 * HID];
    __shared__ float sR1[IN1 * HID];
    __shared__ float sB1[HID];
    for (int i = threadIdx.x; i < RELS * IN1 * HID; i += blockDim.x) sW1[i] = W1[i];
    for (int i = threadIdx.x; i < IN1 * HID; i += blockDim.x) sR1[i] = root1[i];
    for (int i = threadIdx.x; i < HID; i += blockDim.x) sB1[i] = bias1[i];
    __syncthreads();
    int n = blockIdx.x * blockDim.x + threadIdx.x;
    if (n >= N) return;

    float acc[HID];
    float xv0 = x[3 * n + 0], xv1 = x[3 * n + 1], xv2 = x[3 * n + 2];
#pragma unroll
    for (int o = 0; o < HID; ++o)
        acc[o] = sB1[o] + xv0 * sR1[0 * HID + o] + xv1 * sR1[1 * HID + o] + xv2 * sR1[2 * HID + o];

#pragma unroll
    for (int r = 0; r < RELS; ++r) {
        unsigned m0w = mxq[((size_t)n * 3 + r) * 2];
        unsigned m1w = mxq[((size_t)n * 3 + r) * 2 + 1];
        float m0 = bf_lo(m0w), m1 = bf_hi(m0w), m2 = bf_lo(m1w);
        const float* w = sW1 + r * IN1 * HID;
#pragma unroll
        for (int o = 0; o < HID; ++o)
            acc[o] += m0 * w[0 * HID + o] + m1 * w[1 * HID + o] + m2 * w[2 * HID + o];
    }

    float hv[HID];
#pragma unroll
    for (int o = 0; o < HID; ++o) hv[o] = fmaxf(acc[o], 0.f);

    unsigned q[8];
#pragma unroll
    for (int j = 0; j < 8; ++j) q[j] = pack_bf16(hv[2 * j], hv[2 * j + 1]);
    uint4* hp = reinterpret_cast<uint4*>(hq + (size_t)n * 8);
    hp[0] = make_uint4(q[0], q[1], q[2], q[3]);
    hp[1] = make_uint4(q[4], q[5], q[6], q[7]);

    unsigned f8[4];
#pragma unroll
    for (int j = 0; j < 4; ++j) {
        int w = 0;
        w = __builtin_amdgcn_cvt_pk_fp8_f32(hv[4 * j + 0], hv[4 * j + 1], w, false);
        w = __builtin_amdgcn_cvt_pk_fp8_f32(hv[4 * j + 2], hv[4 * j + 3], w, true);
        f8[j] = (unsigned)w;
    }
    hq8[n] = make_uint4(f8[0], f8[1], f8[2], f8[3]);
}

// ---------------- layer2a: per (r,n) segment: mean(h8[src]) @ W2[r] -> partialq (bf16) --
__global__ void k_layer2a(const int* __restrict__ off_g, const unsigned* __restrict__ csr,
                          const uint4* __restrict__ hq8, const float* __restrict__ W2,
                          unsigned* __restrict__ partialq, int N) {
    __shared__ float sW2[RELS * HID * OUT2];
    for (int i = threadIdx.x; i < RELS * HID * OUT2; i += blockDim.x) sW2[i] = W2[i];
    __syncthreads();
    int seg = blockIdx.x * blockDim.x + threadIdx.x;
    if (seg >= 3 * N) return;
    int r = seg % 3;
    int a = off_g[seg], bnd = off_g[seg + 1];

    float s[HID];
#pragma unroll
    for (int i = 0; i < HID; ++i) s[i] = 0.f;
    int e = a;
    for (; e + 4 <= bnd; e += 4) {
        unsigned i0 = __builtin_nontemporal_load(csr + e);
        unsigned i1 = __builtin_nontemporal_load(csr + e + 1);
        unsigned i2 = __builtin_nontemporal_load(csr + e + 2);
        unsigned i3 = __builtin_nontemporal_load(csr + e + 3);
        uint4 q0 = hq8[i0], q1 = hq8[i1], q2 = hq8[i2], q3 = hq8[i3];
        acc_fp8row(q0, s);
        acc_fp8row(q1, s);
        acc_fp8row(q2, s);
        acc_fp8row(q3, s);
    }
    for (; e < bnd; ++e) {
        uint4 q = hq8[__builtin_nontemporal_load(csr + e)];
        acc_fp8row(q, s);
    }
    float inv = 1.0f / fmaxf((float)(bnd - a), 1.0f);
    float o8[OUT2];
#pragma unroll
    for (int o = 0; o < OUT2; ++o) o8[o] = 0.f;
    const float* w = sW2 + r * HID * OUT2;
#pragma unroll
    for (int i = 0; i < HID; ++i) {
        float sv = s[i] * inv;
#pragma unroll
        for (int o = 0; o < OUT2; ++o) o8[o] += sv * w[i * OUT2 + o];
    }
    unsigned* p = partialq + (size_t)seg * 4;
    __builtin_nontemporal_store(pack_bf16(o8[0], o8[1]), p);
    __builtin_nontemporal_store(pack_bf16(o8[2], o8[3]), p + 1);
    __builtin_nontemporal_store(pack_bf16(o8[4], o8[5]), p + 2);
    __builtin_nontemporal_store(pack_bf16(o8[6], o8[7]), p + 3);
}

// ---------------- layer2b: partials + h@root2 + bias2 -> log_softmax ----------------
__global__ void k_layer2b(const unsigned* __restrict__ hq, const uint4* __restrict__ partialq,
                          const float* __restrict__ root2, const float* __restrict__ bias2,
                          float* __restrict__ out, int N) {
    __shared__ float sR2[HID * OUT2];
    __shared__ float sB2[OUT2];
    for (int i = threadIdx.x; i < HID * OUT2; i += blockDim.x) sR2[i] = root2[i];
    for (int i = threadIdx.x; i < OUT2; i += blockDim.x) sB2[i] = bias2[i];
    __syncthreads();
    int n = blockIdx.x * blockDim.x + threadIdx.x;
    if (n >= N) return;

    float acc[OUT2];
#pragma unroll
    for (int o = 0; o < OUT2; ++o) acc[o] = sB2[o];
#pragma unroll
    for (int r = 0; r < RELS; ++r) {
        uint4 P = partialq[(size_t)n * 3 + r];
        acc[0] += bf_lo(P.x); acc[1] += bf_hi(P.x);
        acc[2] += bf_lo(P.y); acc[3] += bf_hi(P.y);
        acc[4] += bf_lo(P.z); acc[5] += bf_hi(P.z);
        acc[6] += bf_lo(P.w); acc[7] += bf_hi(P.w);
    }

    const uint4* hp = reinterpret_cast<const uint4*>(hq + (size_t)n * 8);
    uint4 q0 = hp[0], q1 = hp[1];
    float hv[HID] = {
        bf_lo(q0.x), bf_hi(q0.x), bf_lo(q0.y), bf_hi(q0.y),
        bf_lo(q0.z), bf_hi(q0.z), bf_lo(q0.w), bf_hi(q0.w),
        bf_lo(q1.x), bf_hi(q1.x), bf_lo(q1.y), bf_hi(q1.y),
        bf_lo(q1.z), bf_hi(q1.z), bf_lo(q1.w), bf_hi(q1.w)
    };
#pragma unroll
    for (int i = 0; i < HID; ++i)
#pragma unroll
        for (int o = 0; o < OUT2; ++o) acc[o] += hv[i] * sR2[i * OUT2 + o];

    float mx = acc[0];
#pragma unroll
    for (int o = 1; o < OUT2; ++o) mx = fmaxf(mx, acc[o]);
    float ssum = 0.f;
#pragma unroll
    for (int o = 0; o < OUT2; ++o) ssum += expf(acc[o] - mx);
    float lse = logf(ssum) + mx;
    float* op = out + (size_t)n * OUT2;
    float4 lo = {acc[0] - lse, acc[1] - lse, acc[2] - lse, acc[3] - lse};
    float4 hi = {acc[4] - lse, acc[5] - lse, acc[6] - lse, acc[7] - lse};
    *reinterpret_cast<float4*>(op) = lo;
    *reinterpret_cast<float4*>(op + 4) = hi;
}

extern "C" void kernel_launch(void* const* d_in, const int* in_sizes, int n_in,
                              void* d_out, int out_size, void* d_ws, size_t ws_size,
                              hipStream_t stream) {
    const float* x      = (const float*)d_in[0];
    const int*   eidx   = (const int*)d_in[1];
    const int*   etype  = (const int*)d_in[2];
    const float* basis1 = (const float*)d_in[3];
    const float* comp1  = (const float*)d_in[4];
    const float* root1  = (const float*)d_in[5];
    const float* bias1  = (const float*)d_in[6];
    const float* basis2 = (const float*)d_in[7];
    const float* comp2  = (const float*)d_in[8];
    const float* root2  = (const float*)d_in[9];
    const float* bias2  = (const float*)d_in[10];
    float* out = (float*)d_out;

    const int N = in_sizes[0] / IN1;
    const int E = in_sizes[2];
    const int B = in_sizes[3] / (IN1 * HID);

    const int* src = eidx;
    const int* dst = eidx + E;

    const int NBUCK = (N + BW - 1) / BW;        // 782
    const int NT    = (E + TILE - 1) / TILE;    // 1563
    const int SLEN  = NBUCK * NT;

    char* wsb = (char*)d_ws;
    size_t off_w = 0;
    auto alloc_w = [&](size_t words) {
        void* p = wsb + off_w * 4;
        off_w += (words + 15) & ~(size_t)15;
        return p;
    };
    int*      cnt   = (int*)alloc_w(SLEN);          // scanned in place -> off_e
    int*      bsums = (int*)alloc_w(1024);
    unsigned* part  = (unsigned*)alloc_w(E);        // reused after pass C (see below)
    unsigned* csr   = (unsigned*)alloc_w(E);
    int*      offg  = (int*)alloc_w((size_t)N * 3 + 16);
    float*    W1    = (float*)alloc_w(RELS * IN1 * HID);
    float*    W2    = (float*)alloc_w(RELS * HID * OUT2);
    unsigned* hq    = (unsigned*)alloc_w((size_t)N * 8);   // h in bf16, 32B per node
    uint2*    xq    = (uint2*)alloc_w((size_t)N * 2);      // x in bf16x3, 8B per node
    // aliases inside dead part[] (raw edges consumed by bucket_sort):
    //   partialq: 3N uint4 (bf16 partials)  @ part + 0       (12N words)
    //   mxq:      3N uint2 (bf16 means)     @ part + 12N     (6N words)
    //   hq8:      N  uint4 (fp8 h rows)     @ part + 18N     (4N words)   [22N <= E]
    unsigned* partialq = part;
    unsigned* mxq      = part + (size_t)12 * N;
    uint4*    hq8      = (uint4*)(part + (size_t)18 * N);

    k_compute_W<<<1, 384, 0, stream>>>(basis1, comp1, basis2, comp2, B, W1, W2);

    int grdN = (N + 255) / 256;
    k_pack_x<<<grdN, 256, 0, stream>>>(x, xq, N);

    k_part_count<<<NT, TILE_T, 0, stream>>>(dst, cnt, E, NBUCK, NT);

    int NB = (SLEN + SCAN_TILE - 1) / SCAN_TILE;
    k_scan_block<<<NB, SCAN_BLOCK, 0, stream>>>(cnt, bsums, SLEN);
    k_scan_top<<<1, 1024, 0, stream>>>(bsums, NB);
    k_scan_add<<<(SLEN + 255) / 256, 256, 0, stream>>>(cnt, bsums, SLEN);

    k_part_scatter<<<NT, TILE_T, 0, stream>>>(src, dst, etype, cnt, part, E, NBUCK, NT);

    k_bucket_sort<<<NBUCK, BW, 0, stream>>>(cnt, part, csr, offg, E, NBUCK, NT, N);

    int NSEG = 3 * N;
    int grdS = (NSEG + 255) / 256;
    k_layer1a<<<grdS, 256, 0, stream>>>(offg, csr, xq, mxq, NSEG);
    k_layer1b<<<grdN, 256, 0, stream>>>(x, mxq, W1, root1, bias1, hq, hq8, N);

    k_layer2a<<<grdS, 256, 0, stream>>>(offg, csr, hq8, W2, partialq, N);

    k_layer2b<<<grdN, 256, 0, stream>>>(hq, (const uint4*)partialq, root2, bias2, out, N);
}